// Round 13
// baseline (177.054 us; speedup 1.0000x reference)
//
#include <hip/hip_runtime.h>

#define NN 100000
#define NE 1600000
#define NF 128
#define NH 64
#define NK 20
#define SBK 512                     // sort-bucket: nodes per bucket
#define NSB ((NN + SBK - 1) / SBK)  // 196 buckets
#define CAP 9216                    // fixed coarse capacity per bucket (mean 8163 + 11.7 sigma)
#define CT 4096                     // edges per coarse-scatter block
#define PAD 8
#define MAXPAIRS (size_t(NE) + size_t(PAD) * NN)   // 2.4M pairs

static constexpr float ALPHA = 0.2f;

typedef unsigned short u16;
typedef unsigned int u32;

// ---- workspace layout (aligned to 256B) ----
constexpr size_t alup(size_t x) { return (x + 255) & ~size_t(255); }
constexpr size_t O_FLAG   = 0;                                    // 4 B
constexpr size_t O_GCNT   = 64;                                   // 4 B (epair allocator)
constexpr size_t O_DINV   = 256;                                  // NN f32
constexpr size_t O_HIST   = alup(O_DINV + size_t(NN) * 4);        // NN i32 (real counts)
constexpr size_t O_OFF    = alup(O_HIST + size_t(NN) * 4);        // NN i32 (segment starts)
constexpr size_t O_BCUR   = alup(O_OFF  + size_t(NN) * 4);        // NSB i32 (coarse cursors)
constexpr size_t O_COARSE = alup(O_BCUR + size_t(NSB) * 4);       // NSB*CAP uint2 (14.5 MB)
constexpr size_t O_EPAIR  = alup(O_COARSE + size_t(NSB) * CAP * 8); // MAXPAIRS int2 (19.2 MB)
constexpr size_t O_SUP    = alup(O_EPAIR + MAXPAIRS * 8);         // NN*NH bf16 (12.8 MB)
// total ~ 47.5 MB

__device__ __forceinline__ u16 f2bf(float f) {   // RNE float->bf16
  u32 u = __float_as_uint(f);
  u32 r = (u + 0x7fffu + ((u >> 16) & 1u)) >> 16;
  return (u16)r;
}

// edge_index dtype probe + init bucket cursors + zero epair allocator.
__global__ __launch_bounds__(256) void k_detect(const void* ei, int* flag, int* bcur, int* gcnt) {
  __shared__ int bad;
  if (threadIdx.x == 0) { bad = 0; *gcnt = 0; }
  if (threadIdx.x < NSB) bcur[threadIdx.x] = threadIdx.x * CAP;
  __syncthreads();
  const long long* p = (const long long*)ei;
  int ok = 1;
#pragma unroll
  for (int k = 0; k < 4; ++k) {
    long long v = p[threadIdx.x * 4 + k];
    if (v < 0 || v >= NN) ok = 0;
  }
  if (!ok) atomicOr(&bad, 1);
  __syncthreads();
  if (threadIdx.x == 0) *flag = bad ? 0 : 1;
}

// coarse scatter: bin edges by dst-bucket into fixed-capacity regions;
// LDS ranking -> contiguous writes; bucket frontier (196 lines) stays in L2.
__global__ __launch_bounds__(256) void k_coarse(const void* ei, const int* __restrict__ flag,
                                                const float* __restrict__ w,
                                                int* bcur, uint2* __restrict__ coarse) {
  __shared__ int lh[NSB];
  __shared__ int lbase[NSB];
  int t = threadIdx.x;
  for (int i = t; i < NSB; i += 256) lh[i] = 0;
  __syncthreads();
  int base = blockIdx.x * CT;
  int is64 = *flag;
  u32 key[16]; int wb[16], bk[16], lr[16];
#pragma unroll
  for (int k = 0; k < 16; ++k) {
    int e = base + k * 256 + t;
    if (e < NE) {
      int s, d;
      if (is64) { const long long* p = (const long long*)ei; s = (int)p[e]; d = (int)p[NE + e]; }
      else      { const int*       p = (const int*)ei;       s = p[e];      d = p[NE + e]; }
      int bb = d >> 9, dlo = d & 511;
      key[k] = (u32)s | ((u32)dlo << 17);     // src:17 | dlo:9
      wb[k]  = __float_as_int(w[e]);
      bk[k]  = bb;
      lr[k]  = atomicAdd(&lh[bb], 1);
    }
  }
  __syncthreads();
  if (t < NSB) { int c = lh[t]; if (c) lbase[t] = atomicAdd(&bcur[t], c); }
  __syncthreads();
#pragma unroll
  for (int k = 0; k < 16; ++k) {
    int e = base + k * 256 + t;
    if (e < NE) coarse[lbase[bk[k]] + lr[k]] = make_uint2(key[k], (u32)wb[k]);
  }
}

// merged nhist+scan+fine: pass 1 counts/weighted-degree from the bucket's
// coarse region; in-block scan of padded counts; bucket base allocated by
// global atomic; pass 2 re-reads coarse (L2-hot) and scatters into epair.
__global__ __launch_bounds__(256) void k_sort(const uint2* __restrict__ coarse,
                                              const int* __restrict__ bcur,
                                              int* __restrict__ gcnt,
                                              int* __restrict__ hist,
                                              float* __restrict__ dinv,
                                              int* __restrict__ off,
                                              int2* __restrict__ epair) {
  __shared__ int cnt[SBK];
  __shared__ float wsum[SBK];
  __shared__ int cur[SBK];
  __shared__ int endi[SBK];
  __shared__ int wtot[4];
  __shared__ int gbase;
  int t = threadIdx.x, b = blockIdx.x;
  for (int i = t; i < SBK; i += 256) { cnt[i] = 0; wsum[i] = 0.f; }
  __syncthreads();
  int s = b * CAP, e = bcur[b];
  for (int j = s + t; j < e; j += 256) {
    uint2 u = coarse[j];
    int dlo = u.x >> 17;
    atomicAdd(&cnt[dlo], 1);
    atomicAdd(&wsum[dlo], __uint_as_float(u.y));
  }
  __syncthreads();
  int n0 = b * SBK + t * 2, n1 = n0 + 1;
  int c0r = cnt[t * 2], c1r = cnt[t * 2 + 1];
  int c0 = (c0r + (PAD - 1)) & ~(PAD - 1);
  int c1 = (c1r + (PAD - 1)) & ~(PAD - 1);
  int sum2 = c0 + c1;
  int lane = t & 63, wv = t >> 6;
  int inc = sum2;
  for (int d = 1; d < 64; d <<= 1) { int tt = __shfl_up(inc, d, 64); if (lane >= d) inc += tt; }
  if (lane == 63) wtot[wv] = inc;
  __syncthreads();
  if (t == 0) gbase = atomicAdd(gcnt, wtot[0] + wtot[1] + wtot[2] + wtot[3]);
  int wbase = 0;
#pragma unroll
  for (int k = 0; k < 4; ++k) if (k < wv) wbase += wtot[k];
  __syncthreads();
  int base0 = gbase + wbase + (inc - sum2);
  int base1 = base0 + c0;
  if (n0 < NN) { off[n0] = base0; hist[n0] = c0r; dinv[n0] = rsqrtf(1.0f + wsum[t * 2]); }
  if (n1 < NN) { off[n1] = base1; hist[n1] = c1r; dinv[n1] = rsqrtf(1.0f + wsum[t * 2 + 1]); }
  cur[t * 2]      = base0;
  cur[t * 2 + 1]  = base1;
  endi[t * 2]     = base0 + c0;
  endi[t * 2 + 1] = base1 + c1;
  __syncthreads();
  for (int j = s + t; j < e; j += 256) {      // pass 2: L2-hot re-read
    uint2 u = coarse[j];
    int dlo = u.x >> 17;
    int src = u.x & 0x1FFFF;
    int pos = atomicAdd(&cur[dlo], 1);
    epair[pos] = make_int2(src, (int)u.y);
  }
  __syncthreads();
#pragma unroll
  for (int h = 0; h < 2; ++h) {               // fill pad tails with (0,0)
    int i = t * 2 + h;
    for (int p = cur[i]; p < endi[i]; ++p) epair[p] = make_int2(0, 0);
  }
}

// sup = bf16( dinv[:,None] * (x @ W) ) ; W (32KB) staged in LDS.
__global__ __launch_bounds__(256) void k_gemm(const float* __restrict__ x,
                                              const float* __restrict__ W,
                                              const float* __restrict__ dinv,
                                              u16* __restrict__ supb) {
  __shared__ float4 Wl[NF * NH / 4];
  const float4* Wg = (const float4*)W;
  for (int i = threadIdx.x; i < NF * NH / 4; i += 256) Wl[i] = Wg[i];
  __syncthreads();
  int lane16 = threadIdx.x & 15;
  int rowin  = threadIdx.x >> 4;
  const float4* x4 = (const float4*)x;
  int rowbase = blockIdx.x * 128;
  for (int r0 = 0; r0 < 128; r0 += 16) {
    int r = rowbase + r0 + rowin;
    if (r >= NN) return;
    float4 acc = make_float4(0.f, 0.f, 0.f, 0.f);
#pragma unroll 8
    for (int kk = 0; kk < NF / 4; ++kk) {
      float4 xv = x4[r * (NF / 4) + kk];
      float4 w0 = Wl[(4 * kk + 0) * 16 + lane16];
      float4 w1 = Wl[(4 * kk + 1) * 16 + lane16];
      float4 w2 = Wl[(4 * kk + 2) * 16 + lane16];
      float4 w3 = Wl[(4 * kk + 3) * 16 + lane16];
      acc.x += xv.x * w0.x + xv.y * w1.x + xv.z * w2.x + xv.w * w3.x;
      acc.y += xv.x * w0.y + xv.y * w1.y + xv.z * w2.y + xv.w * w3.y;
      acc.z += xv.x * w0.z + xv.y * w1.z + xv.z * w2.z + xv.w * w3.z;
      acc.w += xv.x * w0.w + xv.y * w1.w + xv.z * w2.w + xv.w * w3.w;
    }
    float di = dinv[r];
    ushort4 o;
    o.x = f2bf(acc.x * di); o.y = f2bf(acc.y * di);
    o.z = f2bf(acc.z * di); o.w = f2bf(acc.w * di);
    *(ushort4*)&supb[(size_t)r * NH + lane16 * 4] = o;
  }
}

// One wave per node, 2 EDGES PER GATHER: lanes 0-31 take even edges, lanes
// 32-63 odd edges; each lane gathers one dword (2 bf16 features) so one VMEM
// instruction covers two edges' rows. Halves combined with one shfl_xor(32).
// Then the LDS-transpose Student-t head (unchanged).
__global__ __launch_bounds__(256) void k_agg_q(const int2* __restrict__ epair,
                                               const int* __restrict__ off,
                                               const int* __restrict__ hist,
                                               const float* __restrict__ dinv,
                                               const u16* __restrict__ supb,
                                               const float* __restrict__ b,
                                               const float* __restrict__ mu,
                                               float* __restrict__ z,
                                               float* __restrict__ q) {
  __shared__ float muL[NK * 68];    // padded rows break bank aliasing
  __shared__ float zsh[4][64];
  for (int i = threadIdx.x; i < NK * NH; i += 256) muL[(i >> 6) * 68 + (i & 63)] = mu[i];
  __syncthreads();
  int wid  = (blockIdx.x * 256 + threadIdx.x) >> 6;  // node
  int lane = threadIdx.x & 63;
  int wv   = threadIdx.x >> 6;

  int startU = __builtin_amdgcn_readfirstlane(off[wid]);
  int cntU   = __builtin_amdgcn_readfirstlane(hist[wid]);
  int endU   = startU + ((cntU + (PAD - 1)) & ~(PAD - 1));
  float di   = dinv[wid];
  int  hi    = lane >> 5;                       // 0: even edges, 1: odd edges
  u32  loff  = ((u32)(lane & 31)) << 2;         // dword offset within 128B row

  // self-loop: feature pair (2f, 2f+1); upper half contributes 0
  u32 su = *(const u32*)((const char*)supb + (((u32)wid) << 7) + loff);
  float aLo = hi ? 0.f : __uint_as_float(su << 16);
  float aHi = hi ? 0.f : __uint_as_float(su & 0xffff0000u);

  for (int j = startU; j < endU; j += 8) {
    int4 p01 = *(const int4*)&epair[j + 0];
    int4 p23 = *(const int4*)&epair[j + 2];
    int4 p45 = *(const int4*)&epair[j + 4];
    int4 p67 = *(const int4*)&epair[j + 6];
#pragma unroll
    for (int k = 0; k < 4; ++k) {
      int4 p = (k == 0) ? p01 : (k == 1) ? p23 : (k == 2) ? p45 : p67;
      int   src = hi ? p.z : p.x;
      float wgt = __int_as_float(hi ? p.w : p.y);
      u32 u = *(const u32*)((const char*)supb + (((u32)src) << 7) + loff);
      aLo += wgt * __uint_as_float(u << 16);
      aHi += wgt * __uint_as_float(u & 0xffff0000u);
    }
  }
  // combine even/odd halves; both halves end with full sums
  aLo += __shfl_xor(aLo, 32, 64);
  aHi += __shfl_xor(aHi, 32, 64);

  int fp = lane & 31;                           // feature pair index
  float2 bb = *(const float2*)&b[fp * 2];
  float zLo = di * aLo + bb.x;
  float zHi = di * aHi + bb.y;
  if (hi == 0) {
    *(float2*)&z[(size_t)wid * NH + fp * 2] = make_float2(zLo, zHi);
    *(float2*)&zsh[wv][fp * 2] = make_float2(zLo, zHi);
  }

  float qv = 0.f;
  if (lane < NK) {
    const float4* zr = (const float4*)zsh[wv];          // broadcast reads
    const float4* mr = (const float4*)&muL[lane * 68];  // per-lane mu row
    float s0 = 0.f, s1 = 0.f, s2 = 0.f, s3 = 0.f;
#pragma unroll
    for (int j = 0; j < 16; ++j) {
      float4 zv = zr[j];
      float4 mv = mr[j];
      float a0 = zv.x - mv.x, a1 = zv.y - mv.y, a2 = zv.z - mv.z, a3 = zv.w - mv.w;
      s0 += a0 * a0; s1 += a1 * a1; s2 += a2 * a2; s3 += a3 * a3;
    }
    float d2 = (s0 + s1) + (s2 + s3);
    float tq = 1.0f / (1.0f + d2 * (1.0f / ALPHA) + 1e-8f);
    qv = exp2f((ALPHA + 1.0f) * __log2f(tq));   // /2 cancels in normalization
  }
  float ssum = qv;
  for (int o = 32; o; o >>= 1) ssum += __shfl_xor(ssum, o, 64);
  if (lane < NK) q[(size_t)wid * NK + lane] = qv / ssum;
}

extern "C" void kernel_launch(void* const* d_in, const int* in_sizes, int n_in,
                              void* d_out, int out_size, void* d_ws, size_t ws_size,
                              hipStream_t stream) {
  const float* x  = (const float*)d_in[0];
  const void*  ei = d_in[1];
  const float* w  = (const float*)d_in[2];
  const float* W  = (const float*)d_in[3];
  const float* b  = (const float*)d_in[4];
  const float* mu = (const float*)d_in[5];

  char* ws = (char*)d_ws;
  int*   flag   = (int*)(ws + O_FLAG);
  int*   gcnt   = (int*)(ws + O_GCNT);
  float* dinv   = (float*)(ws + O_DINV);
  int*   hist   = (int*)(ws + O_HIST);
  int*   off    = (int*)(ws + O_OFF);
  int*   bcur   = (int*)(ws + O_BCUR);
  uint2* coarse = (uint2*)(ws + O_COARSE);
  int2*  epair  = (int2*)(ws + O_EPAIR);
  u16*   supb   = (u16*)(ws + O_SUP);

  float* z = (float*)d_out;
  float* q = (float*)d_out + (size_t)NN * NH;

  hipLaunchKernelGGL(k_detect, dim3(1),                   dim3(256), 0, stream, ei, flag, bcur, gcnt);
  hipLaunchKernelGGL(k_coarse, dim3((NE + CT - 1) / CT),  dim3(256), 0, stream, ei, flag, w, bcur, coarse);
  hipLaunchKernelGGL(k_sort,   dim3(NSB),                 dim3(256), 0, stream, coarse, bcur, gcnt, hist, dinv, off, epair);
  hipLaunchKernelGGL(k_gemm,   dim3((NN + 127) / 128),    dim3(256), 0, stream, x, W, dinv, supb);
  hipLaunchKernelGGL(k_agg_q,  dim3((NN * 64) / 256),     dim3(256), 0, stream, epair, off, hist, dinv, supb, b, mu, z, q);
}

// Round 14
// 167.575 us; speedup vs baseline: 1.0566x; 1.0566x over previous
//
#include <hip/hip_runtime.h>

#define NN 100000
#define NE 1600000
#define NF 128
#define NH 64
#define NK 20
#define SBK 512                     // sort-bucket: nodes per bucket
#define NSB ((NN + SBK - 1) / SBK)  // 196 buckets
#define CAP 9216                    // fixed coarse capacity per bucket (mean 8163 + 11.7 sigma)
#define CT 4096                     // edges per coarse-scatter block
#define PAD 8
#define MAXPAIRS (size_t(NE) + size_t(PAD) * NN)   // 2.4M pairs

static constexpr float ALPHA = 0.2f;

typedef unsigned short u16;
typedef unsigned int u32;

// ---- workspace layout (aligned to 256B) ----
constexpr size_t alup(size_t x) { return (x + 255) & ~size_t(255); }
constexpr size_t O_FLAG   = 0;                                    // 4 B
constexpr size_t O_GCNT   = 64;                                   // 4 B (epair allocator)
constexpr size_t O_DINV   = 256;                                  // NN f32
constexpr size_t O_HIST   = alup(O_DINV + size_t(NN) * 4);        // NN i32 (real counts)
constexpr size_t O_OFF    = alup(O_HIST + size_t(NN) * 4);        // NN i32 (segment starts)
constexpr size_t O_BCUR   = alup(O_OFF  + size_t(NN) * 4);        // NSB i32 (coarse cursors)
constexpr size_t O_COARSE = alup(O_BCUR + size_t(NSB) * 4);       // NSB*CAP uint2 (14.5 MB)
constexpr size_t O_EPAIR  = alup(O_COARSE + size_t(NSB) * CAP * 8); // MAXPAIRS int2 (19.2 MB)
constexpr size_t O_SUP    = alup(O_EPAIR + MAXPAIRS * 8);         // NN*NH bf16 (12.8 MB)
// total ~ 47.5 MB

__device__ __forceinline__ u16 f2bf(float f) {   // RNE float->bf16
  u32 u = __float_as_uint(f);
  u32 r = (u + 0x7fffu + ((u >> 16) & 1u)) >> 16;
  return (u16)r;
}
__device__ __forceinline__ float bf2f(u16 h) {
  return __uint_as_float(((u32)h) << 16);
}
__device__ __forceinline__ float gath(const u16* supb, u32 byteoff) {
  return bf2f(*(const u16*)((const char*)supb + byteoff));
}

// edge_index dtype probe + init bucket cursors + zero epair allocator.
__global__ __launch_bounds__(256) void k_detect(const void* ei, int* flag, int* bcur, int* gcnt) {
  __shared__ int bad;
  if (threadIdx.x == 0) { bad = 0; *gcnt = 0; }
  if (threadIdx.x < NSB) bcur[threadIdx.x] = threadIdx.x * CAP;
  __syncthreads();
  const long long* p = (const long long*)ei;
  int ok = 1;
#pragma unroll
  for (int k = 0; k < 4; ++k) {
    long long v = p[threadIdx.x * 4 + k];
    if (v < 0 || v >= NN) ok = 0;
  }
  if (!ok) atomicOr(&bad, 1);
  __syncthreads();
  if (threadIdx.x == 0) *flag = bad ? 0 : 1;
}

// coarse scatter: bin edges by dst-bucket into fixed-capacity regions;
// LDS ranking -> contiguous writes; bucket frontier (196 lines) stays in L2.
__global__ __launch_bounds__(256) void k_coarse(const void* ei, const int* __restrict__ flag,
                                                const float* __restrict__ w,
                                                int* bcur, uint2* __restrict__ coarse) {
  __shared__ int lh[NSB];
  __shared__ int lbase[NSB];
  int t = threadIdx.x;
  for (int i = t; i < NSB; i += 256) lh[i] = 0;
  __syncthreads();
  int base = blockIdx.x * CT;
  int is64 = *flag;
  u32 key[16]; int wb[16], bk[16], lr[16];
#pragma unroll
  for (int k = 0; k < 16; ++k) {
    int e = base + k * 256 + t;
    if (e < NE) {
      int s, d;
      if (is64) { const long long* p = (const long long*)ei; s = (int)p[e]; d = (int)p[NE + e]; }
      else      { const int*       p = (const int*)ei;       s = p[e];      d = p[NE + e]; }
      int bb = d >> 9, dlo = d & 511;
      key[k] = (u32)s | ((u32)dlo << 17);     // src:17 | dlo:9
      wb[k]  = __float_as_int(w[e]);
      bk[k]  = bb;
      lr[k]  = atomicAdd(&lh[bb], 1);
    }
  }
  __syncthreads();
  if (t < NSB) { int c = lh[t]; if (c) lbase[t] = atomicAdd(&bcur[t], c); }
  __syncthreads();
#pragma unroll
  for (int k = 0; k < 16; ++k) {
    int e = base + k * 256 + t;
    if (e < NE) coarse[lbase[bk[k]] + lr[k]] = make_uint2(key[k], (u32)wb[k]);
  }
}

// merged nhist+scan+fine: pass 1 counts/weighted-degree from the bucket's
// coarse region; in-block scan of padded counts; bucket base allocated by
// global atomic; pass 2 re-reads coarse (L2-hot) and scatters into epair.
__global__ __launch_bounds__(256) void k_sort(const uint2* __restrict__ coarse,
                                              const int* __restrict__ bcur,
                                              int* __restrict__ gcnt,
                                              int* __restrict__ hist,
                                              float* __restrict__ dinv,
                                              int* __restrict__ off,
                                              int2* __restrict__ epair) {
  __shared__ int cnt[SBK];
  __shared__ float wsum[SBK];
  __shared__ int cur[SBK];
  __shared__ int endi[SBK];
  __shared__ int wtot[4];
  __shared__ int gbase;
  int t = threadIdx.x, b = blockIdx.x;
  for (int i = t; i < SBK; i += 256) { cnt[i] = 0; wsum[i] = 0.f; }
  __syncthreads();
  int s = b * CAP, e = bcur[b];
  for (int j = s + t; j < e; j += 256) {
    uint2 u = coarse[j];
    int dlo = u.x >> 17;
    atomicAdd(&cnt[dlo], 1);
    atomicAdd(&wsum[dlo], __uint_as_float(u.y));
  }
  __syncthreads();
  int n0 = b * SBK + t * 2, n1 = n0 + 1;
  int c0r = cnt[t * 2], c1r = cnt[t * 2 + 1];
  int c0 = (c0r + (PAD - 1)) & ~(PAD - 1);
  int c1 = (c1r + (PAD - 1)) & ~(PAD - 1);
  int sum2 = c0 + c1;
  int lane = t & 63, wv = t >> 6;
  int inc = sum2;
  for (int d = 1; d < 64; d <<= 1) { int tt = __shfl_up(inc, d, 64); if (lane >= d) inc += tt; }
  if (lane == 63) wtot[wv] = inc;
  __syncthreads();
  if (t == 0) gbase = atomicAdd(gcnt, wtot[0] + wtot[1] + wtot[2] + wtot[3]);
  int wbase = 0;
#pragma unroll
  for (int k = 0; k < 4; ++k) if (k < wv) wbase += wtot[k];
  __syncthreads();
  int base0 = gbase + wbase + (inc - sum2);
  int base1 = base0 + c0;
  if (n0 < NN) { off[n0] = base0; hist[n0] = c0r; dinv[n0] = rsqrtf(1.0f + wsum[t * 2]); }
  if (n1 < NN) { off[n1] = base1; hist[n1] = c1r; dinv[n1] = rsqrtf(1.0f + wsum[t * 2 + 1]); }
  cur[t * 2]      = base0;
  cur[t * 2 + 1]  = base1;
  endi[t * 2]     = base0 + c0;
  endi[t * 2 + 1] = base1 + c1;
  __syncthreads();
  for (int j = s + t; j < e; j += 256) {      // pass 2: L2-hot re-read
    uint2 u = coarse[j];
    int dlo = u.x >> 17;
    int src = u.x & 0x1FFFF;
    int pos = atomicAdd(&cur[dlo], 1);
    epair[pos] = make_int2(src, (int)u.y);
  }
  __syncthreads();
#pragma unroll
  for (int h = 0; h < 2; ++h) {               // fill pad tails with (0,0)
    int i = t * 2 + h;
    for (int p = cur[i]; p < endi[i]; ++p) epair[p] = make_int2(0, 0);
  }
}

// sup = bf16( dinv[:,None] * (x @ W) ) ; W (32KB) staged in LDS.
__global__ __launch_bounds__(256) void k_gemm(const float* __restrict__ x,
                                              const float* __restrict__ W,
                                              const float* __restrict__ dinv,
                                              u16* __restrict__ supb) {
  __shared__ float4 Wl[NF * NH / 4];
  const float4* Wg = (const float4*)W;
  for (int i = threadIdx.x; i < NF * NH / 4; i += 256) Wl[i] = Wg[i];
  __syncthreads();
  int lane16 = threadIdx.x & 15;
  int rowin  = threadIdx.x >> 4;
  const float4* x4 = (const float4*)x;
  int rowbase = blockIdx.x * 128;
  for (int r0 = 0; r0 < 128; r0 += 16) {
    int r = rowbase + r0 + rowin;
    if (r >= NN) return;
    float4 acc = make_float4(0.f, 0.f, 0.f, 0.f);
#pragma unroll 8
    for (int kk = 0; kk < NF / 4; ++kk) {
      float4 xv = x4[r * (NF / 4) + kk];
      float4 w0 = Wl[(4 * kk + 0) * 16 + lane16];
      float4 w1 = Wl[(4 * kk + 1) * 16 + lane16];
      float4 w2 = Wl[(4 * kk + 2) * 16 + lane16];
      float4 w3 = Wl[(4 * kk + 3) * 16 + lane16];
      acc.x += xv.x * w0.x + xv.y * w1.x + xv.z * w2.x + xv.w * w3.x;
      acc.y += xv.x * w0.y + xv.y * w1.y + xv.z * w2.y + xv.w * w3.y;
      acc.z += xv.x * w0.z + xv.y * w1.z + xv.z * w2.z + xv.w * w3.z;
      acc.w += xv.x * w0.w + xv.y * w1.w + xv.z * w2.w + xv.w * w3.w;
    }
    float di = dinv[r];
    ushort4 o;
    o.x = f2bf(acc.x * di); o.y = f2bf(acc.y * di);
    o.z = f2bf(acc.z * di); o.w = f2bf(acc.w * di);
    *(ushort4*)&supb[(size_t)r * NH + lane16 * 4] = o;
  }
}

// One wave per node: round-12 edge loop (1 ushort gather + 1 shift + 1 fmac
// per edge; 8 in flight), then 40-LANE Student-t head: lanes 0-19 do cluster
// k over features 0-31, lanes 32-51 over features 32-63 (mu in LDS), one
// shfl_xor(32) combine. Halves the head's issue cost vs 20-lane form.
__global__ __launch_bounds__(256) void k_agg_q(const int2* __restrict__ epair,
                                               const int* __restrict__ off,
                                               const int* __restrict__ hist,
                                               const float* __restrict__ dinv,
                                               const u16* __restrict__ supb,
                                               const float* __restrict__ b,
                                               const float* __restrict__ mu,
                                               float* __restrict__ z,
                                               float* __restrict__ q) {
  __shared__ float muL[NK * 68];    // stride 68 words: f4-aligned, spreads banks
  __shared__ float zsh[4][64];
  for (int i = threadIdx.x; i < NK * NH; i += 256) muL[(i >> 6) * 68 + (i & 63)] = mu[i];
  __syncthreads();
  int wid  = (blockIdx.x * 256 + threadIdx.x) >> 6;  // node
  int lane = threadIdx.x & 63;                       // feature
  int wv   = threadIdx.x >> 6;

  int startU = __builtin_amdgcn_readfirstlane(off[wid]);
  int cntU   = __builtin_amdgcn_readfirstlane(hist[wid]);
  int endU   = startU + ((cntU + (PAD - 1)) & ~(PAD - 1));
  float di  = dinv[wid];
  u32 loff = (u32)lane << 1;
  float acc0 = gath(supb, ((u32)wid << 7) + loff);   // self-loop term
  float acc1 = 0.f;

  for (int j = startU; j < endU; j += 8) {
    int4 p01 = *(const int4*)&epair[j + 0];
    int4 p23 = *(const int4*)&epair[j + 2];
    int4 p45 = *(const int4*)&epair[j + 4];
    int4 p67 = *(const int4*)&epair[j + 6];
    float v0 = gath(supb, ((u32)p01.x << 7) + loff);
    float v1 = gath(supb, ((u32)p01.z << 7) + loff);
    float v2 = gath(supb, ((u32)p23.x << 7) + loff);
    float v3 = gath(supb, ((u32)p23.z << 7) + loff);
    float v4 = gath(supb, ((u32)p45.x << 7) + loff);
    float v5 = gath(supb, ((u32)p45.z << 7) + loff);
    float v6 = gath(supb, ((u32)p67.x << 7) + loff);
    float v7 = gath(supb, ((u32)p67.z << 7) + loff);
    acc0 += __int_as_float(p01.y) * v0;
    acc1 += __int_as_float(p01.w) * v1;
    acc0 += __int_as_float(p23.y) * v2;
    acc1 += __int_as_float(p23.w) * v3;
    acc0 += __int_as_float(p45.y) * v4;
    acc1 += __int_as_float(p45.w) * v5;
    acc0 += __int_as_float(p67.y) * v6;
    acc1 += __int_as_float(p67.w) * v7;
  }

  float zz = di * (acc0 + acc1) + b[lane];
  z[(size_t)wid * NH + lane] = zz;
  zsh[wv][lane] = zz;   // same-wave write->read

  // 40-lane head: k = lane&31 (<20 active), h = lane>>5 selects feature half
  int kk = lane & 31;
  int h  = lane >> 5;
  float s = 0.f;
  if (kk < NK) {
    const float4* zr = (const float4*)&zsh[wv][h * 32];        // broadcast reads
    const float4* mr = (const float4*)&muL[kk * 68 + h * 32];  // per-lane mu half-row
    float s0 = 0.f, s1 = 0.f;
#pragma unroll
    for (int j = 0; j < 8; ++j) {
      float4 zv = zr[j];
      float4 mv = mr[j];
      float a0 = zv.x - mv.x, a1 = zv.y - mv.y, a2 = zv.z - mv.z, a3 = zv.w - mv.w;
      s0 += a0 * a0 + a1 * a1;
      s1 += a2 * a2 + a3 * a3;
    }
    s = s0 + s1;
  }
  s += __shfl_xor(s, 32, 64);   // combine feature halves

  float qv = 0.f;
  if (lane < NK) {
    float tq = 1.0f / (1.0f + s * (1.0f / ALPHA) + 1e-8f);
    qv = exp2f((ALPHA + 1.0f) * __log2f(tq));   // /2 cancels in normalization
  }
  float ssum = qv;
  for (int o = 32; o; o >>= 1) ssum += __shfl_xor(ssum, o, 64);
  if (lane < NK) q[(size_t)wid * NK + lane] = qv / ssum;
}

extern "C" void kernel_launch(void* const* d_in, const int* in_sizes, int n_in,
                              void* d_out, int out_size, void* d_ws, size_t ws_size,
                              hipStream_t stream) {
  const float* x  = (const float*)d_in[0];
  const void*  ei = d_in[1];
  const float* w  = (const float*)d_in[2];
  const float* W  = (const float*)d_in[3];
  const float* b  = (const float*)d_in[4];
  const float* mu = (const float*)d_in[5];

  char* ws = (char*)d_ws;
  int*   flag   = (int*)(ws + O_FLAG);
  int*   gcnt   = (int*)(ws + O_GCNT);
  float* dinv   = (float*)(ws + O_DINV);
  int*   hist   = (int*)(ws + O_HIST);
  int*   off    = (int*)(ws + O_OFF);
  int*   bcur   = (int*)(ws + O_BCUR);
  uint2* coarse = (uint2*)(ws + O_COARSE);
  int2*  epair  = (int2*)(ws + O_EPAIR);
  u16*   supb   = (u16*)(ws + O_SUP);

  float* z = (float*)d_out;
  float* q = (float*)d_out + (size_t)NN * NH;

  hipLaunchKernelGGL(k_detect, dim3(1),                   dim3(256), 0, stream, ei, flag, bcur, gcnt);
  hipLaunchKernelGGL(k_coarse, dim3((NE + CT - 1) / CT),  dim3(256), 0, stream, ei, flag, w, bcur, coarse);
  hipLaunchKernelGGL(k_sort,   dim3(NSB),                 dim3(256), 0, stream, coarse, bcur, gcnt, hist, dinv, off, epair);
  hipLaunchKernelGGL(k_gemm,   dim3((NN + 127) / 128),    dim3(256), 0, stream, x, W, dinv, supb);
  hipLaunchKernelGGL(k_agg_q,  dim3((NN * 64) / 256),     dim3(256), 0, stream, epair, off, hist, dinv, supb, b, mu, z, q);
}

// Round 15
// 153.923 us; speedup vs baseline: 1.1503x; 1.0887x over previous
//
#include <hip/hip_runtime.h>

#define NN 100000
#define NE 1600000
#define NF 128
#define NH 64
#define NK 20
#define SBK 512                     // sort-bucket: nodes per bucket
#define NSB ((NN + SBK - 1) / SBK)  // 196 buckets
#define CAP 9216                    // fixed coarse capacity per bucket (mean 8163 + 11.7 sigma)
#define CT 4096                     // edges per coarse-scatter block
#define PAD 8
#define MAXPAIRS (size_t(NE) + size_t(PAD) * NN)   // 2.4M pairs

static constexpr float ALPHA = 0.2f;

typedef unsigned short u16;
typedef unsigned int u32;

// ---- workspace layout (aligned to 256B) ----
constexpr size_t alup(size_t x) { return (x + 255) & ~size_t(255); }
constexpr size_t O_FLAG   = 0;                                    // 4 B
constexpr size_t O_GCNT   = 64;                                   // 4 B (epair allocator)
constexpr size_t O_DINV   = 256;                                  // NN f32
constexpr size_t O_HIST   = alup(O_DINV + size_t(NN) * 4);        // NN i32 (real counts)
constexpr size_t O_OFF    = alup(O_HIST + size_t(NN) * 4);        // NN i32 (segment starts)
constexpr size_t O_BCUR   = alup(O_OFF  + size_t(NN) * 4);        // NSB i32 (coarse cursors)
constexpr size_t O_COARSE = alup(O_BCUR + size_t(NSB) * 4);       // NSB*CAP uint2 (14.5 MB)
constexpr size_t O_EPAIR  = alup(O_COARSE + size_t(NSB) * CAP * 8); // MAXPAIRS int2 (19.2 MB)
constexpr size_t O_SUP    = alup(O_EPAIR + MAXPAIRS * 8);         // NN*NH bf16 (12.8 MB)
// total ~ 47.5 MB

__device__ __forceinline__ u16 f2bf(float f) {   // RNE float->bf16
  u32 u = __float_as_uint(f);
  u32 r = (u + 0x7fffu + ((u >> 16) & 1u)) >> 16;
  return (u16)r;
}

// edge_index dtype probe + init bucket cursors + zero epair allocator.
__global__ __launch_bounds__(256) void k_detect(const void* ei, int* flag, int* bcur, int* gcnt) {
  __shared__ int bad;
  if (threadIdx.x == 0) { bad = 0; *gcnt = 0; }
  if (threadIdx.x < NSB) bcur[threadIdx.x] = threadIdx.x * CAP;
  __syncthreads();
  const long long* p = (const long long*)ei;
  int ok = 1;
#pragma unroll
  for (int k = 0; k < 4; ++k) {
    long long v = p[threadIdx.x * 4 + k];
    if (v < 0 || v >= NN) ok = 0;
  }
  if (!ok) atomicOr(&bad, 1);
  __syncthreads();
  if (threadIdx.x == 0) *flag = bad ? 0 : 1;
}

// coarse scatter: bin edges by dst-bucket into fixed-capacity regions;
// LDS ranking -> contiguous writes; bucket frontier (196 lines) stays in L2.
__global__ __launch_bounds__(256) void k_coarse(const void* ei, const int* __restrict__ flag,
                                                const float* __restrict__ w,
                                                int* bcur, uint2* __restrict__ coarse) {
  __shared__ int lh[NSB];
  __shared__ int lbase[NSB];
  int t = threadIdx.x;
  for (int i = t; i < NSB; i += 256) lh[i] = 0;
  __syncthreads();
  int base = blockIdx.x * CT;
  int is64 = *flag;
  u32 key[16]; int wb[16], bk[16], lr[16];
#pragma unroll
  for (int k = 0; k < 16; ++k) {
    int e = base + k * 256 + t;
    if (e < NE) {
      int s, d;
      if (is64) { const long long* p = (const long long*)ei; s = (int)p[e]; d = (int)p[NE + e]; }
      else      { const int*       p = (const int*)ei;       s = p[e];      d = p[NE + e]; }
      int bb = d >> 9, dlo = d & 511;
      key[k] = (u32)s | ((u32)dlo << 17);     // src:17 | dlo:9
      wb[k]  = __float_as_int(w[e]);
      bk[k]  = bb;
      lr[k]  = atomicAdd(&lh[bb], 1);
    }
  }
  __syncthreads();
  if (t < NSB) { int c = lh[t]; if (c) lbase[t] = atomicAdd(&bcur[t], c); }
  __syncthreads();
#pragma unroll
  for (int k = 0; k < 16; ++k) {
    int e = base + k * 256 + t;
    if (e < NE) coarse[lbase[bk[k]] + lr[k]] = make_uint2(key[k], (u32)wb[k]);
  }
}

// merged nhist+scan+fine: pass 1 counts/weighted-degree from the bucket's
// coarse region; in-block scan of padded counts; bucket base allocated by
// global atomic; pass 2 re-reads coarse (L2-hot) and scatters into epair.
__global__ __launch_bounds__(256) void k_sort(const uint2* __restrict__ coarse,
                                              const int* __restrict__ bcur,
                                              int* __restrict__ gcnt,
                                              int* __restrict__ hist,
                                              float* __restrict__ dinv,
                                              int* __restrict__ off,
                                              int2* __restrict__ epair) {
  __shared__ int cnt[SBK];
  __shared__ float wsum[SBK];
  __shared__ int cur[SBK];
  __shared__ int endi[SBK];
  __shared__ int wtot[4];
  __shared__ int gbase;
  int t = threadIdx.x, b = blockIdx.x;
  for (int i = t; i < SBK; i += 256) { cnt[i] = 0; wsum[i] = 0.f; }
  __syncthreads();
  int s = b * CAP, e = bcur[b];
  for (int j = s + t; j < e; j += 256) {
    uint2 u = coarse[j];
    int dlo = u.x >> 17;
    atomicAdd(&cnt[dlo], 1);
    atomicAdd(&wsum[dlo], __uint_as_float(u.y));
  }
  __syncthreads();
  int n0 = b * SBK + t * 2, n1 = n0 + 1;
  int c0r = cnt[t * 2], c1r = cnt[t * 2 + 1];
  int c0 = (c0r + (PAD - 1)) & ~(PAD - 1);
  int c1 = (c1r + (PAD - 1)) & ~(PAD - 1);
  int sum2 = c0 + c1;
  int lane = t & 63, wv = t >> 6;
  int inc = sum2;
  for (int d = 1; d < 64; d <<= 1) { int tt = __shfl_up(inc, d, 64); if (lane >= d) inc += tt; }
  if (lane == 63) wtot[wv] = inc;
  __syncthreads();
  if (t == 0) gbase = atomicAdd(gcnt, wtot[0] + wtot[1] + wtot[2] + wtot[3]);
  int wbase = 0;
#pragma unroll
  for (int k = 0; k < 4; ++k) if (k < wv) wbase += wtot[k];
  __syncthreads();
  int base0 = gbase + wbase + (inc - sum2);
  int base1 = base0 + c0;
  if (n0 < NN) { off[n0] = base0; hist[n0] = c0r; dinv[n0] = rsqrtf(1.0f + wsum[t * 2]); }
  if (n1 < NN) { off[n1] = base1; hist[n1] = c1r; dinv[n1] = rsqrtf(1.0f + wsum[t * 2 + 1]); }
  cur[t * 2]      = base0;
  cur[t * 2 + 1]  = base1;
  endi[t * 2]     = base0 + c0;
  endi[t * 2 + 1] = base1 + c1;
  __syncthreads();
  for (int j = s + t; j < e; j += 256) {      // pass 2: L2-hot re-read
    uint2 u = coarse[j];
    int dlo = u.x >> 17;
    int src = u.x & 0x1FFFF;
    int pos = atomicAdd(&cur[dlo], 1);
    epair[pos] = make_int2(src, (int)u.y);
  }
  __syncthreads();
#pragma unroll
  for (int h = 0; h < 2; ++h) {               // fill pad tails with (0,0)
    int i = t * 2 + h;
    for (int p = cur[i]; p < endi[i]; ++p) epair[p] = make_int2(0, 0);
  }
}

// sup = bf16( dinv[:,None] * (x @ W) ) ; W (32KB) staged in LDS.
__global__ __launch_bounds__(256) void k_gemm(const float* __restrict__ x,
                                              const float* __restrict__ W,
                                              const float* __restrict__ dinv,
                                              u16* __restrict__ supb) {
  __shared__ float4 Wl[NF * NH / 4];
  const float4* Wg = (const float4*)W;
  for (int i = threadIdx.x; i < NF * NH / 4; i += 256) Wl[i] = Wg[i];
  __syncthreads();
  int lane16 = threadIdx.x & 15;
  int rowin  = threadIdx.x >> 4;
  const float4* x4 = (const float4*)x;
  int rowbase = blockIdx.x * 128;
  for (int r0 = 0; r0 < 128; r0 += 16) {
    int r = rowbase + r0 + rowin;
    if (r >= NN) return;
    float4 acc = make_float4(0.f, 0.f, 0.f, 0.f);
#pragma unroll 8
    for (int kk = 0; kk < NF / 4; ++kk) {
      float4 xv = x4[r * (NF / 4) + kk];
      float4 w0 = Wl[(4 * kk + 0) * 16 + lane16];
      float4 w1 = Wl[(4 * kk + 1) * 16 + lane16];
      float4 w2 = Wl[(4 * kk + 2) * 16 + lane16];
      float4 w3 = Wl[(4 * kk + 3) * 16 + lane16];
      acc.x += xv.x * w0.x + xv.y * w1.x + xv.z * w2.x + xv.w * w3.x;
      acc.y += xv.x * w0.y + xv.y * w1.y + xv.z * w2.y + xv.w * w3.y;
      acc.z += xv.x * w0.z + xv.y * w1.z + xv.z * w2.z + xv.w * w3.z;
      acc.w += xv.x * w0.w + xv.y * w1.w + xv.z * w2.w + xv.w * w3.w;
    }
    float di = dinv[r];
    ushort4 o;
    o.x = f2bf(acc.x * di); o.y = f2bf(acc.y * di);
    o.z = f2bf(acc.z * di); o.w = f2bf(acc.w * di);
    *(ushort4*)&supb[(size_t)r * NH + lane16 * 4] = o;
  }
}

// TWO nodes per wave: lanes 0-31 = node 2p, lanes 32-63 = node 2p+1.
// Each lane covers 2 features (one dword = 2 bf16), so ONE VMEM gather
// serves a full 128B row for each half simultaneously (0.75 VMEM/edge).
// Each half loads its OWN epair stream (per-half base address -> no selects,
// the round-13 mistake). Loop runs max(itersA, itersB), exec-masked.
// Head: 40-lane form run twice (once per node); same aggregate cost.
__global__ __launch_bounds__(256) void k_agg_q(const int2* __restrict__ epair,
                                               const int* __restrict__ off,
                                               const int* __restrict__ hist,
                                               const float* __restrict__ dinv,
                                               const u16* __restrict__ supb,
                                               const float* __restrict__ b,
                                               const float* __restrict__ mu,
                                               float* __restrict__ z,
                                               float* __restrict__ q) {
  __shared__ float muL[NK * 68];    // stride 68 words: f4-aligned, spreads banks
  __shared__ float zsh[4][2][64];
  for (int i = threadIdx.x; i < NK * NH; i += 256) muL[(i >> 6) * 68 + (i & 63)] = mu[i];
  __syncthreads();
  int pid  = (blockIdx.x * 256 + threadIdx.x) >> 6;  // node pair
  int lane = threadIdx.x & 63;
  int wv   = threadIdx.x >> 6;
  int hi   = lane >> 5;                              // which node of the pair
  int hl   = lane & 31;                              // feature pair index
  int node = pid * 2 + hi;

  int start = off[node];                             // uniform within half
  int cnt   = hist[node];
  int iters = ((cnt + (PAD - 1)) & ~(PAD - 1)) >> 3;
  int oit   = __shfl_xor(iters, 32, 64);
  int maxit = __builtin_amdgcn_readfirstlane(iters > oit ? iters : oit);
  float di  = dinv[node];
  u32 loff  = (u32)hl << 2;                          // dword offset in 128B row

  u32 su = *(const u32*)((const char*)supb + (((u32)node) << 7) + loff);  // self-loop
  float aLo = __uint_as_float(su << 16);
  float aHi = __uint_as_float(su & 0xffff0000u);

  for (int it = 0; it < maxit; ++it) {
    if (it < iters) {                                // per-half exec mask
      int j = start + it * 8;
      int4 p01 = *(const int4*)&epair[j + 0];
      int4 p23 = *(const int4*)&epair[j + 2];
      int4 p45 = *(const int4*)&epair[j + 4];
      int4 p67 = *(const int4*)&epair[j + 6];
      u32 u0 = *(const u32*)((const char*)supb + (((u32)p01.x) << 7) + loff);
      u32 u1 = *(const u32*)((const char*)supb + (((u32)p01.z) << 7) + loff);
      u32 u2 = *(const u32*)((const char*)supb + (((u32)p23.x) << 7) + loff);
      u32 u3 = *(const u32*)((const char*)supb + (((u32)p23.z) << 7) + loff);
      u32 u4 = *(const u32*)((const char*)supb + (((u32)p45.x) << 7) + loff);
      u32 u5 = *(const u32*)((const char*)supb + (((u32)p45.z) << 7) + loff);
      u32 u6 = *(const u32*)((const char*)supb + (((u32)p67.x) << 7) + loff);
      u32 u7 = *(const u32*)((const char*)supb + (((u32)p67.z) << 7) + loff);
      float w0 = __int_as_float(p01.y), w1 = __int_as_float(p01.w);
      float w2 = __int_as_float(p23.y), w3 = __int_as_float(p23.w);
      float w4 = __int_as_float(p45.y), w5 = __int_as_float(p45.w);
      float w6 = __int_as_float(p67.y), w7 = __int_as_float(p67.w);
      aLo += w0 * __uint_as_float(u0 << 16);
      aHi += w0 * __uint_as_float(u0 & 0xffff0000u);
      aLo += w1 * __uint_as_float(u1 << 16);
      aHi += w1 * __uint_as_float(u1 & 0xffff0000u);
      aLo += w2 * __uint_as_float(u2 << 16);
      aHi += w2 * __uint_as_float(u2 & 0xffff0000u);
      aLo += w3 * __uint_as_float(u3 << 16);
      aHi += w3 * __uint_as_float(u3 & 0xffff0000u);
      aLo += w4 * __uint_as_float(u4 << 16);
      aHi += w4 * __uint_as_float(u4 & 0xffff0000u);
      aLo += w5 * __uint_as_float(u5 << 16);
      aHi += w5 * __uint_as_float(u5 & 0xffff0000u);
      aLo += w6 * __uint_as_float(u6 << 16);
      aHi += w6 * __uint_as_float(u6 & 0xffff0000u);
      aLo += w7 * __uint_as_float(u7 << 16);
      aHi += w7 * __uint_as_float(u7 & 0xffff0000u);
    }
  }

  float2 bb = *(const float2*)&b[hl * 2];
  float zLo = di * aLo + bb.x;
  float zHi = di * aHi + bb.y;
  *(float2*)&z[(size_t)node * NH + hl * 2] = make_float2(zLo, zHi);
  *(float2*)&zsh[wv][hi][hl * 2] = make_float2(zLo, zHi);  // same-wave write->read

  // 40-lane head, run for each node of the pair
  int kk = lane & 31;
  int h  = lane >> 5;
#pragma unroll
  for (int n = 0; n < 2; ++n) {
    float s = 0.f;
    if (kk < NK) {
      const float4* zr = (const float4*)&zsh[wv][n][h * 32];     // broadcast reads
      const float4* mr = (const float4*)&muL[kk * 68 + h * 32];  // per-lane mu half-row
      float s0 = 0.f, s1 = 0.f;
#pragma unroll
      for (int j = 0; j < 8; ++j) {
        float4 zv = zr[j];
        float4 mv = mr[j];
        float a0 = zv.x - mv.x, a1 = zv.y - mv.y, a2 = zv.z - mv.z, a3 = zv.w - mv.w;
        s0 += a0 * a0 + a1 * a1;
        s1 += a2 * a2 + a3 * a3;
      }
      s = s0 + s1;
    }
    s += __shfl_xor(s, 32, 64);   // combine feature halves

    float qv = 0.f;
    if (lane < NK) {
      float tq = 1.0f / (1.0f + s * (1.0f / ALPHA) + 1e-8f);
      qv = exp2f((ALPHA + 1.0f) * __log2f(tq));   // /2 cancels in normalization
    }
    float ssum = qv;
    for (int o = 32; o; o >>= 1) ssum += __shfl_xor(ssum, o, 64);
    if (lane < NK) q[(size_t)(pid * 2 + n) * NK + lane] = qv / ssum;
  }
}

extern "C" void kernel_launch(void* const* d_in, const int* in_sizes, int n_in,
                              void* d_out, int out_size, void* d_ws, size_t ws_size,
                              hipStream_t stream) {
  const float* x  = (const float*)d_in[0];
  const void*  ei = d_in[1];
  const float* w  = (const float*)d_in[2];
  const float* W  = (const float*)d_in[3];
  const float* b  = (const float*)d_in[4];
  const float* mu = (const float*)d_in[5];

  char* ws = (char*)d_ws;
  int*   flag   = (int*)(ws + O_FLAG);
  int*   gcnt   = (int*)(ws + O_GCNT);
  float* dinv   = (float*)(ws + O_DINV);
  int*   hist   = (int*)(ws + O_HIST);
  int*   off    = (int*)(ws + O_OFF);
  int*   bcur   = (int*)(ws + O_BCUR);
  uint2* coarse = (uint2*)(ws + O_COARSE);
  int2*  epair  = (int2*)(ws + O_EPAIR);
  u16*   supb   = (u16*)(ws + O_SUP);

  float* z = (float*)d_out;
  float* q = (float*)d_out + (size_t)NN * NH;

  hipLaunchKernelGGL(k_detect, dim3(1),                   dim3(256), 0, stream, ei, flag, bcur, gcnt);
  hipLaunchKernelGGL(k_coarse, dim3((NE + CT - 1) / CT),  dim3(256), 0, stream, ei, flag, w, bcur, coarse);
  hipLaunchKernelGGL(k_sort,   dim3(NSB),                 dim3(256), 0, stream, coarse, bcur, gcnt, hist, dinv, off, epair);
  hipLaunchKernelGGL(k_gemm,   dim3((NN + 127) / 128),    dim3(256), 0, stream, x, W, dinv, supb);
  hipLaunchKernelGGL(k_agg_q,  dim3((NN / 2 * 64) / 256), dim3(256), 0, stream, epair, off, hist, dinv, supb, b, mu, z, q);
}

// Round 16
// 153.364 us; speedup vs baseline: 1.1545x; 1.0036x over previous
//
#include <hip/hip_runtime.h>

#define NN 100000
#define NE 1600000
#define NF 128
#define NH 64
#define NK 20
#define SBK 512                     // sort-bucket: nodes per bucket
#define NSB ((NN + SBK - 1) / SBK)  // 196 buckets
#define CAP 9216                    // fixed coarse capacity per bucket (mean 8163 + 11.7 sigma)
#define CT 4096                     // edges per coarse-scatter block
#define PAD 8
#define MAXPAIRS (size_t(NE) + size_t(PAD) * NN)   // 2.4M pairs

static constexpr float ALPHA = 0.2f;

typedef unsigned short u16;
typedef unsigned int u32;

// ---- workspace layout (aligned to 256B) ----
constexpr size_t alup(size_t x) { return (x + 255) & ~size_t(255); }
constexpr size_t O_FLAG   = 0;                                    // 4 B
constexpr size_t O_GCNT   = 64;                                   // 4 B (epair allocator)
constexpr size_t O_DINV   = 256;                                  // NN f32
constexpr size_t O_HIST   = alup(O_DINV + size_t(NN) * 4);        // NN i32 (real counts)
constexpr size_t O_OFF    = alup(O_HIST + size_t(NN) * 4);        // NN i32 (segment starts)
constexpr size_t O_BCUR   = alup(O_OFF  + size_t(NN) * 4);        // NSB i32 (coarse cursors)
constexpr size_t O_COARSE = alup(O_BCUR + size_t(NSB) * 4);       // NSB*CAP uint2 (14.5 MB)
constexpr size_t O_EPAIR  = alup(O_COARSE + size_t(NSB) * CAP * 8); // MAXPAIRS int2 (19.2 MB)
constexpr size_t O_SUP    = alup(O_EPAIR + MAXPAIRS * 8);         // NN*NH bf16 (12.8 MB)
// total ~ 47.5 MB

__device__ __forceinline__ u16 f2bf(float f) {   // RNE float->bf16
  u32 u = __float_as_uint(f);
  u32 r = (u + 0x7fffu + ((u >> 16) & 1u)) >> 16;
  return (u16)r;
}

// edge_index dtype probe + init bucket cursors + zero epair allocator.
__global__ __launch_bounds__(256) void k_detect(const void* ei, int* flag, int* bcur, int* gcnt) {
  __shared__ int bad;
  if (threadIdx.x == 0) { bad = 0; *gcnt = 0; }
  if (threadIdx.x < NSB) bcur[threadIdx.x] = threadIdx.x * CAP;
  __syncthreads();
  const long long* p = (const long long*)ei;
  int ok = 1;
#pragma unroll
  for (int k = 0; k < 4; ++k) {
    long long v = p[threadIdx.x * 4 + k];
    if (v < 0 || v >= NN) ok = 0;
  }
  if (!ok) atomicOr(&bad, 1);
  __syncthreads();
  if (threadIdx.x == 0) *flag = bad ? 0 : 1;
}

// coarse scatter: bin edges by dst-bucket into fixed-capacity regions;
// LDS ranking -> contiguous writes; bucket frontier (196 lines) stays in L2.
__global__ __launch_bounds__(256) void k_coarse(const void* ei, const int* __restrict__ flag,
                                                const float* __restrict__ w,
                                                int* bcur, uint2* __restrict__ coarse) {
  __shared__ int lh[NSB];
  __shared__ int lbase[NSB];
  int t = threadIdx.x;
  for (int i = t; i < NSB; i += 256) lh[i] = 0;
  __syncthreads();
  int base = blockIdx.x * CT;
  int is64 = *flag;
  u32 key[16]; int wb[16], bk[16], lr[16];
#pragma unroll
  for (int k = 0; k < 16; ++k) {
    int e = base + k * 256 + t;
    if (e < NE) {
      int s, d;
      if (is64) { const long long* p = (const long long*)ei; s = (int)p[e]; d = (int)p[NE + e]; }
      else      { const int*       p = (const int*)ei;       s = p[e];      d = p[NE + e]; }
      int bb = d >> 9, dlo = d & 511;
      key[k] = (u32)s | ((u32)dlo << 17);     // src:17 | dlo:9
      wb[k]  = __float_as_int(w[e]);
      bk[k]  = bb;
      lr[k]  = atomicAdd(&lh[bb], 1);
    }
  }
  __syncthreads();
  if (t < NSB) { int c = lh[t]; if (c) lbase[t] = atomicAdd(&bcur[t], c); }
  __syncthreads();
#pragma unroll
  for (int k = 0; k < 16; ++k) {
    int e = base + k * 256 + t;
    if (e < NE) coarse[lbase[bk[k]] + lr[k]] = make_uint2(key[k], (u32)wb[k]);
  }
}

// merged nhist+scan+fine: pass 1 counts/weighted-degree from the bucket's
// coarse region; in-block scan of padded counts; bucket base allocated by
// global atomic; pass 2 re-reads coarse (L2-hot) and scatters into epair.
__global__ __launch_bounds__(256) void k_sort(const uint2* __restrict__ coarse,
                                              const int* __restrict__ bcur,
                                              int* __restrict__ gcnt,
                                              int* __restrict__ hist,
                                              float* __restrict__ dinv,
                                              int* __restrict__ off,
                                              int2* __restrict__ epair) {
  __shared__ int cnt[SBK];
  __shared__ float wsum[SBK];
  __shared__ int cur[SBK];
  __shared__ int endi[SBK];
  __shared__ int wtot[4];
  __shared__ int gbase;
  int t = threadIdx.x, b = blockIdx.x;
  for (int i = t; i < SBK; i += 256) { cnt[i] = 0; wsum[i] = 0.f; }
  __syncthreads();
  int s = b * CAP, e = bcur[b];
  for (int j = s + t; j < e; j += 256) {
    uint2 u = coarse[j];
    int dlo = u.x >> 17;
    atomicAdd(&cnt[dlo], 1);
    atomicAdd(&wsum[dlo], __uint_as_float(u.y));
  }
  __syncthreads();
  int n0 = b * SBK + t * 2, n1 = n0 + 1;
  int c0r = cnt[t * 2], c1r = cnt[t * 2 + 1];
  int c0 = (c0r + (PAD - 1)) & ~(PAD - 1);
  int c1 = (c1r + (PAD - 1)) & ~(PAD - 1);
  int sum2 = c0 + c1;
  int lane = t & 63, wv = t >> 6;
  int inc = sum2;
  for (int d = 1; d < 64; d <<= 1) { int tt = __shfl_up(inc, d, 64); if (lane >= d) inc += tt; }
  if (lane == 63) wtot[wv] = inc;
  __syncthreads();
  if (t == 0) gbase = atomicAdd(gcnt, wtot[0] + wtot[1] + wtot[2] + wtot[3]);
  int wbase = 0;
#pragma unroll
  for (int k = 0; k < 4; ++k) if (k < wv) wbase += wtot[k];
  __syncthreads();
  int base0 = gbase + wbase + (inc - sum2);
  int base1 = base0 + c0;
  if (n0 < NN) { off[n0] = base0; hist[n0] = c0r; dinv[n0] = rsqrtf(1.0f + wsum[t * 2]); }
  if (n1 < NN) { off[n1] = base1; hist[n1] = c1r; dinv[n1] = rsqrtf(1.0f + wsum[t * 2 + 1]); }
  cur[t * 2]      = base0;
  cur[t * 2 + 1]  = base1;
  endi[t * 2]     = base0 + c0;
  endi[t * 2 + 1] = base1 + c1;
  __syncthreads();
  for (int j = s + t; j < e; j += 256) {      // pass 2: L2-hot re-read
    uint2 u = coarse[j];
    int dlo = u.x >> 17;
    int src = u.x & 0x1FFFF;
    int pos = atomicAdd(&cur[dlo], 1);
    epair[pos] = make_int2(src, (int)u.y);
  }
  __syncthreads();
#pragma unroll
  for (int h = 0; h < 2; ++h) {               // fill pad tails with (0,0)
    int i = t * 2 + h;
    for (int p = cur[i]; p < endi[i]; ++p) epair[p] = make_int2(0, 0);
  }
}

// sup = bf16( dinv[:,None] * (x @ W) ) ; W (32KB) in LDS, REGISTER-TILED
// 8 rows/thread so each W read is amortized over 8 rows (LDS reads/thread
// 1024 -> 128; round-15 profile showed k_gemm DS-pipe bound at 62us).
__global__ __launch_bounds__(256) void k_gemm(const float* __restrict__ x,
                                              const float* __restrict__ W,
                                              const float* __restrict__ dinv,
                                              u16* __restrict__ supb) {
  __shared__ float4 Wl[NF * NH / 4];
  const float4* Wg = (const float4*)W;
  for (int i = threadIdx.x; i < NF * NH / 4; i += 256) Wl[i] = Wg[i];
  __syncthreads();
  int lane16 = threadIdx.x & 15;   // column group: cols [lane16*4, lane16*4+4)
  int rowin  = threadIdx.x >> 4;   // 0..15
  const float4* x4 = (const float4*)x;
  int rowbase = blockIdx.x * 128;

  int r[8];
#pragma unroll
  for (int i = 0; i < 8; ++i) {
    int rr = rowbase + rowin + i * 16;
    r[i] = rr < NN ? rr : NN - 1;            // clamp: safe reads, stores predicated
  }
  float4 acc[8];
#pragma unroll
  for (int i = 0; i < 8; ++i) acc[i] = make_float4(0.f, 0.f, 0.f, 0.f);

  for (int kk = 0; kk < NF / 4; ++kk) {
    float4 w0 = Wl[(4 * kk + 0) * 16 + lane16];
    float4 w1 = Wl[(4 * kk + 1) * 16 + lane16];
    float4 w2 = Wl[(4 * kk + 2) * 16 + lane16];
    float4 w3 = Wl[(4 * kk + 3) * 16 + lane16];
#pragma unroll
    for (int i = 0; i < 8; ++i) {
      float4 xv = x4[r[i] * (NF / 4) + kk];
      acc[i].x += xv.x * w0.x + xv.y * w1.x + xv.z * w2.x + xv.w * w3.x;
      acc[i].y += xv.x * w0.y + xv.y * w1.y + xv.z * w2.y + xv.w * w3.y;
      acc[i].z += xv.x * w0.z + xv.y * w1.z + xv.z * w2.z + xv.w * w3.z;
      acc[i].w += xv.x * w0.w + xv.y * w1.w + xv.z * w2.w + xv.w * w3.w;
    }
  }

#pragma unroll
  for (int i = 0; i < 8; ++i) {
    int rr = rowbase + rowin + i * 16;
    if (rr < NN) {
      float di = dinv[rr];
      ushort4 o;
      o.x = f2bf(acc[i].x * di); o.y = f2bf(acc[i].y * di);
      o.z = f2bf(acc[i].z * di); o.w = f2bf(acc[i].w * di);
      *(ushort4*)&supb[(size_t)rr * NH + lane16 * 4] = o;
    }
  }
}

// TWO nodes per wave: lanes 0-31 = node 2p, lanes 32-63 = node 2p+1.
// Each lane covers 2 features (one dword = 2 bf16), so ONE VMEM gather
// serves a full 128B row for each half simultaneously (0.75 VMEM/edge).
// Each half loads its OWN epair stream; loop runs max(itersA, itersB).
// Head: 40-lane form run twice (once per node); same aggregate cost.
__global__ __launch_bounds__(256) void k_agg_q(const int2* __restrict__ epair,
                                               const int* __restrict__ off,
                                               const int* __restrict__ hist,
                                               const float* __restrict__ dinv,
                                               const u16* __restrict__ supb,
                                               const float* __restrict__ b,
                                               const float* __restrict__ mu,
                                               float* __restrict__ z,
                                               float* __restrict__ q) {
  __shared__ float muL[NK * 68];    // stride 68 words: f4-aligned, spreads banks
  __shared__ float zsh[4][2][64];
  for (int i = threadIdx.x; i < NK * NH; i += 256) muL[(i >> 6) * 68 + (i & 63)] = mu[i];
  __syncthreads();
  int pid  = (blockIdx.x * 256 + threadIdx.x) >> 6;  // node pair
  int lane = threadIdx.x & 63;
  int wv   = threadIdx.x >> 6;
  int hi   = lane >> 5;                              // which node of the pair
  int hl   = lane & 31;                              // feature pair index
  int node = pid * 2 + hi;

  int start = off[node];                             // uniform within half
  int cnt   = hist[node];
  int iters = ((cnt + (PAD - 1)) & ~(PAD - 1)) >> 3;
  int oit   = __shfl_xor(iters, 32, 64);
  int maxit = __builtin_amdgcn_readfirstlane(iters > oit ? iters : oit);
  float di  = dinv[node];
  u32 loff  = (u32)hl << 2;                          // dword offset in 128B row

  u32 su = *(const u32*)((const char*)supb + (((u32)node) << 7) + loff);  // self-loop
  float aLo = __uint_as_float(su << 16);
  float aHi = __uint_as_float(su & 0xffff0000u);

  for (int it = 0; it < maxit; ++it) {
    if (it < iters) {                                // per-half exec mask
      int j = start + it * 8;
      int4 p01 = *(const int4*)&epair[j + 0];
      int4 p23 = *(const int4*)&epair[j + 2];
      int4 p45 = *(const int4*)&epair[j + 4];
      int4 p67 = *(const int4*)&epair[j + 6];
      u32 u0 = *(const u32*)((const char*)supb + (((u32)p01.x) << 7) + loff);
      u32 u1 = *(const u32*)((const char*)supb + (((u32)p01.z) << 7) + loff);
      u32 u2 = *(const u32*)((const char*)supb + (((u32)p23.x) << 7) + loff);
      u32 u3 = *(const u32*)((const char*)supb + (((u32)p23.z) << 7) + loff);
      u32 u4 = *(const u32*)((const char*)supb + (((u32)p45.x) << 7) + loff);
      u32 u5 = *(const u32*)((const char*)supb + (((u32)p45.z) << 7) + loff);
      u32 u6 = *(const u32*)((const char*)supb + (((u32)p67.x) << 7) + loff);
      u32 u7 = *(const u32*)((const char*)supb + (((u32)p67.z) << 7) + loff);
      float w0 = __int_as_float(p01.y), w1 = __int_as_float(p01.w);
      float w2 = __int_as_float(p23.y), w3 = __int_as_float(p23.w);
      float w4 = __int_as_float(p45.y), w5 = __int_as_float(p45.w);
      float w6 = __int_as_float(p67.y), w7 = __int_as_float(p67.w);
      aLo += w0 * __uint_as_float(u0 << 16);
      aHi += w0 * __uint_as_float(u0 & 0xffff0000u);
      aLo += w1 * __uint_as_float(u1 << 16);
      aHi += w1 * __uint_as_float(u1 & 0xffff0000u);
      aLo += w2 * __uint_as_float(u2 << 16);
      aHi += w2 * __uint_as_float(u2 & 0xffff0000u);
      aLo += w3 * __uint_as_float(u3 << 16);
      aHi += w3 * __uint_as_float(u3 & 0xffff0000u);
      aLo += w4 * __uint_as_float(u4 << 16);
      aHi += w4 * __uint_as_float(u4 & 0xffff0000u);
      aLo += w5 * __uint_as_float(u5 << 16);
      aHi += w5 * __uint_as_float(u5 & 0xffff0000u);
      aLo += w6 * __uint_as_float(u6 << 16);
      aHi += w6 * __uint_as_float(u6 & 0xffff0000u);
      aLo += w7 * __uint_as_float(u7 << 16);
      aHi += w7 * __uint_as_float(u7 & 0xffff0000u);
    }
  }

  float2 bb = *(const float2*)&b[hl * 2];
  float zLo = di * aLo + bb.x;
  float zHi = di * aHi + bb.y;
  *(float2*)&z[(size_t)node * NH + hl * 2] = make_float2(zLo, zHi);
  *(float2*)&zsh[wv][hi][hl * 2] = make_float2(zLo, zHi);  // same-wave write->read

  // 40-lane head, run for each node of the pair
  int kk = lane & 31;
  int h  = lane >> 5;
#pragma unroll
  for (int n = 0; n < 2; ++n) {
    float s = 0.f;
    if (kk < NK) {
      const float4* zr = (const float4*)&zsh[wv][n][h * 32];     // broadcast reads
      const float4* mr = (const float4*)&muL[kk * 68 + h * 32];  // per-lane mu half-row
      float s0 = 0.f, s1 = 0.f;
#pragma unroll
      for (int j = 0; j < 8; ++j) {
        float4 zv = zr[j];
        float4 mv = mr[j];
        float a0 = zv.x - mv.x, a1 = zv.y - mv.y, a2 = zv.z - mv.z, a3 = zv.w - mv.w;
        s0 += a0 * a0 + a1 * a1;
        s1 += a2 * a2 + a3 * a3;
      }
      s = s0 + s1;
    }
    s += __shfl_xor(s, 32, 64);   // combine feature halves

    float qv = 0.f;
    if (lane < NK) {
      float tq = 1.0f / (1.0f + s * (1.0f / ALPHA) + 1e-8f);
      qv = exp2f((ALPHA + 1.0f) * __log2f(tq));   // /2 cancels in normalization
    }
    float ssum = qv;
    for (int o = 32; o; o >>= 1) ssum += __shfl_xor(ssum, o, 64);
    if (lane < NK) q[(size_t)(pid * 2 + n) * NK + lane] = qv / ssum;
  }
}

extern "C" void kernel_launch(void* const* d_in, const int* in_sizes, int n_in,
                              void* d_out, int out_size, void* d_ws, size_t ws_size,
                              hipStream_t stream) {
  const float* x  = (const float*)d_in[0];
  const void*  ei = d_in[1];
  const float* w  = (const float*)d_in[2];
  const float* W  = (const float*)d_in[3];
  const float* b  = (const float*)d_in[4];
  const float* mu = (const float*)d_in[5];

  char* ws = (char*)d_ws;
  int*   flag   = (int*)(ws + O_FLAG);
  int*   gcnt   = (int*)(ws + O_GCNT);
  float* dinv   = (float*)(ws + O_DINV);
  int*   hist   = (int*)(ws + O_HIST);
  int*   off    = (int*)(ws + O_OFF);
  int*   bcur   = (int*)(ws + O_BCUR);
  uint2* coarse = (uint2*)(ws + O_COARSE);
  int2*  epair  = (int2*)(ws + O_EPAIR);
  u16*   supb   = (u16*)(ws + O_SUP);

  float* z = (float*)d_out;
  float* q = (float*)d_out + (size_t)NN * NH;

  hipLaunchKernelGGL(k_detect, dim3(1),                   dim3(256), 0, stream, ei, flag, bcur, gcnt);
  hipLaunchKernelGGL(k_coarse, dim3((NE + CT - 1) / CT),  dim3(256), 0, stream, ei, flag, w, bcur, coarse);
  hipLaunchKernelGGL(k_sort,   dim3(NSB),                 dim3(256), 0, stream, coarse, bcur, gcnt, hist, dinv, off, epair);
  hipLaunchKernelGGL(k_gemm,   dim3((NN + 127) / 128),    dim3(256), 0, stream, x, W, dinv, supb);
  hipLaunchKernelGGL(k_agg_q,  dim3((NN / 2 * 64) / 256), dim3(256), 0, stream, epair, off, hist, dinv, supb, b, mu, z, q);
}

// Round 17
// 146.544 us; speedup vs baseline: 1.2082x; 1.0465x over previous
//
#include <hip/hip_runtime.h>

#define NN 100000
#define NE 1600000
#define NF 128
#define NH 64
#define NK 20
#define SBK 512                     // sort-bucket: nodes per bucket
#define NSB ((NN + SBK - 1) / SBK)  // 196 buckets
#define CAP 9216                    // fixed coarse capacity per bucket (mean 8163 + 11.7 sigma)
#define CT 4096                     // edges per coarse-scatter block
#define PAD 8
#define GR 64                       // gemm rows per block (4 rows/thread)
#define MAXPAIRS (size_t(NE) + size_t(PAD) * NN)   // 2.4M pairs

static constexpr float ALPHA = 0.2f;

typedef unsigned short u16;
typedef unsigned int u32;

// ---- workspace layout (aligned to 256B) ----
constexpr size_t alup(size_t x) { return (x + 255) & ~size_t(255); }
constexpr size_t O_FLAG   = 0;                                    // 4 B
constexpr size_t O_GCNT   = 64;                                   // 4 B (epair allocator)
constexpr size_t O_DINV   = 256;                                  // NN f32
constexpr size_t O_HIST   = alup(O_DINV + size_t(NN) * 4);        // NN i32 (real counts)
constexpr size_t O_OFF    = alup(O_HIST + size_t(NN) * 4);        // NN i32 (segment starts)
constexpr size_t O_BCUR   = alup(O_OFF  + size_t(NN) * 4);        // NSB i32 (coarse cursors)
constexpr size_t O_COARSE = alup(O_BCUR + size_t(NSB) * 4);       // NSB*CAP uint2 (14.5 MB)
constexpr size_t O_EPAIR  = alup(O_COARSE + size_t(NSB) * CAP * 8); // MAXPAIRS int2 (19.2 MB)
constexpr size_t O_SUP    = alup(O_EPAIR + MAXPAIRS * 8);         // NN*NH bf16 (12.8 MB)
// total ~ 47.5 MB

__device__ __forceinline__ u16 f2bf(float f) {   // RNE float->bf16
  u32 u = __float_as_uint(f);
  u32 r = (u + 0x7fffu + ((u >> 16) & 1u)) >> 16;
  return (u16)r;
}

// edge_index dtype probe + init bucket cursors + zero epair allocator.
__global__ __launch_bounds__(256) void k_detect(const void* ei, int* flag, int* bcur, int* gcnt) {
  __shared__ int bad;
  if (threadIdx.x == 0) { bad = 0; *gcnt = 0; }
  if (threadIdx.x < NSB) bcur[threadIdx.x] = threadIdx.x * CAP;
  __syncthreads();
  const long long* p = (const long long*)ei;
  int ok = 1;
#pragma unroll
  for (int k = 0; k < 4; ++k) {
    long long v = p[threadIdx.x * 4 + k];
    if (v < 0 || v >= NN) ok = 0;
  }
  if (!ok) atomicOr(&bad, 1);
  __syncthreads();
  if (threadIdx.x == 0) *flag = bad ? 0 : 1;
}

// coarse scatter: bin edges by dst-bucket into fixed-capacity regions;
// LDS ranking -> contiguous writes; bucket frontier (196 lines) stays in L2.
__global__ __launch_bounds__(256) void k_coarse(const void* ei, const int* __restrict__ flag,
                                                const float* __restrict__ w,
                                                int* bcur, uint2* __restrict__ coarse) {
  __shared__ int lh[NSB];
  __shared__ int lbase[NSB];
  int t = threadIdx.x;
  for (int i = t; i < NSB; i += 256) lh[i] = 0;
  __syncthreads();
  int base = blockIdx.x * CT;
  int is64 = *flag;
  u32 key[16]; int wb[16], bk[16], lr[16];
#pragma unroll
  for (int k = 0; k < 16; ++k) {
    int e = base + k * 256 + t;
    if (e < NE) {
      int s, d;
      if (is64) { const long long* p = (const long long*)ei; s = (int)p[e]; d = (int)p[NE + e]; }
      else      { const int*       p = (const int*)ei;       s = p[e];      d = p[NE + e]; }
      int bb = d >> 9, dlo = d & 511;
      key[k] = (u32)s | ((u32)dlo << 17);     // src:17 | dlo:9
      wb[k]  = __float_as_int(w[e]);
      bk[k]  = bb;
      lr[k]  = atomicAdd(&lh[bb], 1);
    }
  }
  __syncthreads();
  if (t < NSB) { int c = lh[t]; if (c) lbase[t] = atomicAdd(&bcur[t], c); }
  __syncthreads();
#pragma unroll
  for (int k = 0; k < 16; ++k) {
    int e = base + k * 256 + t;
    if (e < NE) coarse[lbase[bk[k]] + lr[k]] = make_uint2(key[k], (u32)wb[k]);
  }
}

// merged nhist+scan+fine: pass 1 counts/weighted-degree from the bucket's
// coarse region; in-block scan of padded counts; bucket base allocated by
// global atomic; pass 2 re-reads coarse (L2-hot) and scatters into epair.
__global__ __launch_bounds__(256) void k_sort(const uint2* __restrict__ coarse,
                                              const int* __restrict__ bcur,
                                              int* __restrict__ gcnt,
                                              int* __restrict__ hist,
                                              float* __restrict__ dinv,
                                              int* __restrict__ off,
                                              int2* __restrict__ epair) {
  __shared__ int cnt[SBK];
  __shared__ float wsum[SBK];
  __shared__ int cur[SBK];
  __shared__ int endi[SBK];
  __shared__ int wtot[4];
  __shared__ int gbase;
  int t = threadIdx.x, b = blockIdx.x;
  for (int i = t; i < SBK; i += 256) { cnt[i] = 0; wsum[i] = 0.f; }
  __syncthreads();
  int s = b * CAP, e = bcur[b];
  for (int j = s + t; j < e; j += 256) {
    uint2 u = coarse[j];
    int dlo = u.x >> 17;
    atomicAdd(&cnt[dlo], 1);
    atomicAdd(&wsum[dlo], __uint_as_float(u.y));
  }
  __syncthreads();
  int n0 = b * SBK + t * 2, n1 = n0 + 1;
  int c0r = cnt[t * 2], c1r = cnt[t * 2 + 1];
  int c0 = (c0r + (PAD - 1)) & ~(PAD - 1);
  int c1 = (c1r + (PAD - 1)) & ~(PAD - 1);
  int sum2 = c0 + c1;
  int lane = t & 63, wv = t >> 6;
  int inc = sum2;
  for (int d = 1; d < 64; d <<= 1) { int tt = __shfl_up(inc, d, 64); if (lane >= d) inc += tt; }
  if (lane == 63) wtot[wv] = inc;
  __syncthreads();
  if (t == 0) gbase = atomicAdd(gcnt, wtot[0] + wtot[1] + wtot[2] + wtot[3]);
  int wbase = 0;
#pragma unroll
  for (int k = 0; k < 4; ++k) if (k < wv) wbase += wtot[k];
  __syncthreads();
  int base0 = gbase + wbase + (inc - sum2);
  int base1 = base0 + c0;
  if (n0 < NN) { off[n0] = base0; hist[n0] = c0r; dinv[n0] = rsqrtf(1.0f + wsum[t * 2]); }
  if (n1 < NN) { off[n1] = base1; hist[n1] = c1r; dinv[n1] = rsqrtf(1.0f + wsum[t * 2 + 1]); }
  cur[t * 2]      = base0;
  cur[t * 2 + 1]  = base1;
  endi[t * 2]     = base0 + c0;
  endi[t * 2 + 1] = base1 + c1;
  __syncthreads();
  for (int j = s + t; j < e; j += 256) {      // pass 2: L2-hot re-read
    uint2 u = coarse[j];
    int dlo = u.x >> 17;
    int src = u.x & 0x1FFFF;
    int pos = atomicAdd(&cur[dlo], 1);
    epair[pos] = make_int2(src, (int)u.y);
  }
  __syncthreads();
#pragma unroll
  for (int h = 0; h < 2; ++h) {               // fill pad tails with (0,0)
    int i = t * 2 + h;
    for (int p = cur[i]; p < endi[i]; ++p) epair[p] = make_int2(0, 0);
  }
}

// sup = bf16( dinv[:,None] * (x @ W) ) ; W (32KB) in LDS; 64 rows/block
// (4 rows/thread) -> grid 1563 and 5-blocks/CU LDS cap: occupancy 27%->~62%
// (round-16 lesson: gemm is x-load LATENCY bound, not DS bound — add waves).
__global__ __launch_bounds__(256) void k_gemm(const float* __restrict__ x,
                                              const float* __restrict__ W,
                                              const float* __restrict__ dinv,
                                              u16* __restrict__ supb) {
  __shared__ float4 Wl[NF * NH / 4];
  const float4* Wg = (const float4*)W;
  for (int i = threadIdx.x; i < NF * NH / 4; i += 256) Wl[i] = Wg[i];
  __syncthreads();
  int lane16 = threadIdx.x & 15;   // column group: cols [lane16*4, lane16*4+4)
  int rowin  = threadIdx.x >> 4;   // 0..15
  const float4* x4 = (const float4*)x;
  int rowbase = blockIdx.x * GR;

  int r[4];
#pragma unroll
  for (int i = 0; i < 4; ++i) {
    int rr = rowbase + rowin + i * 16;
    r[i] = rr < NN ? rr : NN - 1;            // clamp: safe reads, stores predicated
  }
  float4 acc[4];
#pragma unroll
  for (int i = 0; i < 4; ++i) acc[i] = make_float4(0.f, 0.f, 0.f, 0.f);

  for (int kk = 0; kk < NF / 4; ++kk) {
    float4 w0 = Wl[(4 * kk + 0) * 16 + lane16];
    float4 w1 = Wl[(4 * kk + 1) * 16 + lane16];
    float4 w2 = Wl[(4 * kk + 2) * 16 + lane16];
    float4 w3 = Wl[(4 * kk + 3) * 16 + lane16];
#pragma unroll
    for (int i = 0; i < 4; ++i) {
      float4 xv = x4[r[i] * (NF / 4) + kk];
      acc[i].x += xv.x * w0.x + xv.y * w1.x + xv.z * w2.x + xv.w * w3.x;
      acc[i].y += xv.x * w0.y + xv.y * w1.y + xv.z * w2.y + xv.w * w3.y;
      acc[i].z += xv.x * w0.z + xv.y * w1.z + xv.z * w2.z + xv.w * w3.z;
      acc[i].w += xv.x * w0.w + xv.y * w1.w + xv.z * w2.w + xv.w * w3.w;
    }
  }

#pragma unroll
  for (int i = 0; i < 4; ++i) {
    int rr = rowbase + rowin + i * 16;
    if (rr < NN) {
      float di = dinv[rr];
      ushort4 o;
      o.x = f2bf(acc[i].x * di); o.y = f2bf(acc[i].y * di);
      o.z = f2bf(acc[i].z * di); o.w = f2bf(acc[i].w * di);
      *(ushort4*)&supb[(size_t)rr * NH + lane16 * 4] = o;
    }
  }
}

// TWO nodes per wave: lanes 0-31 = node 2p, lanes 32-63 = node 2p+1.
// Each lane covers 2 features (one dword = 2 bf16), so ONE VMEM gather
// serves a full 128B row for each half simultaneously (0.75 VMEM/edge).
// Each half loads its OWN epair stream; loop runs max(itersA, itersB).
// Head: 40-lane form run twice (once per node); same aggregate cost.
__global__ __launch_bounds__(256) void k_agg_q(const int2* __restrict__ epair,
                                               const int* __restrict__ off,
                                               const int* __restrict__ hist,
                                               const float* __restrict__ dinv,
                                               const u16* __restrict__ supb,
                                               const float* __restrict__ b,
                                               const float* __restrict__ mu,
                                               float* __restrict__ z,
                                               float* __restrict__ q) {
  __shared__ float muL[NK * 68];    // stride 68 words: f4-aligned, spreads banks
  __shared__ float zsh[4][2][64];
  for (int i = threadIdx.x; i < NK * NH; i += 256) muL[(i >> 6) * 68 + (i & 63)] = mu[i];
  __syncthreads();
  int pid  = (blockIdx.x * 256 + threadIdx.x) >> 6;  // node pair
  int lane = threadIdx.x & 63;
  int wv   = threadIdx.x >> 6;
  int hi   = lane >> 5;                              // which node of the pair
  int hl   = lane & 31;                              // feature pair index
  int node = pid * 2 + hi;

  int start = off[node];                             // uniform within half
  int cnt   = hist[node];
  int iters = ((cnt + (PAD - 1)) & ~(PAD - 1)) >> 3;
  int oit   = __shfl_xor(iters, 32, 64);
  int maxit = __builtin_amdgcn_readfirstlane(iters > oit ? iters : oit);
  float di  = dinv[node];
  u32 loff  = (u32)hl << 2;                          // dword offset in 128B row

  u32 su = *(const u32*)((const char*)supb + (((u32)node) << 7) + loff);  // self-loop
  float aLo = __uint_as_float(su << 16);
  float aHi = __uint_as_float(su & 0xffff0000u);

  for (int it = 0; it < maxit; ++it) {
    if (it < iters) {                                // per-half exec mask
      int j = start + it * 8;
      int4 p01 = *(const int4*)&epair[j + 0];
      int4 p23 = *(const int4*)&epair[j + 2];
      int4 p45 = *(const int4*)&epair[j + 4];
      int4 p67 = *(const int4*)&epair[j + 6];
      u32 u0 = *(const u32*)((const char*)supb + (((u32)p01.x) << 7) + loff);
      u32 u1 = *(const u32*)((const char*)supb + (((u32)p01.z) << 7) + loff);
      u32 u2 = *(const u32*)((const char*)supb + (((u32)p23.x) << 7) + loff);
      u32 u3 = *(const u32*)((const char*)supb + (((u32)p23.z) << 7) + loff);
      u32 u4 = *(const u32*)((const char*)supb + (((u32)p45.x) << 7) + loff);
      u32 u5 = *(const u32*)((const char*)supb + (((u32)p45.z) << 7) + loff);
      u32 u6 = *(const u32*)((const char*)supb + (((u32)p67.x) << 7) + loff);
      u32 u7 = *(const u32*)((const char*)supb + (((u32)p67.z) << 7) + loff);
      float w0 = __int_as_float(p01.y), w1 = __int_as_float(p01.w);
      float w2 = __int_as_float(p23.y), w3 = __int_as_float(p23.w);
      float w4 = __int_as_float(p45.y), w5 = __int_as_float(p45.w);
      float w6 = __int_as_float(p67.y), w7 = __int_as_float(p67.w);
      aLo += w0 * __uint_as_float(u0 << 16);
      aHi += w0 * __uint_as_float(u0 & 0xffff0000u);
      aLo += w1 * __uint_as_float(u1 << 16);
      aHi += w1 * __uint_as_float(u1 & 0xffff0000u);
      aLo += w2 * __uint_as_float(u2 << 16);
      aHi += w2 * __uint_as_float(u2 & 0xffff0000u);
      aLo += w3 * __uint_as_float(u3 << 16);
      aHi += w3 * __uint_as_float(u3 & 0xffff0000u);
      aLo += w4 * __uint_as_float(u4 << 16);
      aHi += w4 * __uint_as_float(u4 & 0xffff0000u);
      aLo += w5 * __uint_as_float(u5 << 16);
      aHi += w5 * __uint_as_float(u5 & 0xffff0000u);
      aLo += w6 * __uint_as_float(u6 << 16);
      aHi += w6 * __uint_as_float(u6 & 0xffff0000u);
      aLo += w7 * __uint_as_float(u7 << 16);
      aHi += w7 * __uint_as_float(u7 & 0xffff0000u);
    }
  }

  float2 bb = *(const float2*)&b[hl * 2];
  float zLo = di * aLo + bb.x;
  float zHi = di * aHi + bb.y;
  *(float2*)&z[(size_t)node * NH + hl * 2] = make_float2(zLo, zHi);
  *(float2*)&zsh[wv][hi][hl * 2] = make_float2(zLo, zHi);  // same-wave write->read

  // 40-lane head, run for each node of the pair
  int kk = lane & 31;
  int h  = lane >> 5;
#pragma unroll
  for (int n = 0; n < 2; ++n) {
    float s = 0.f;
    if (kk < NK) {
      const float4* zr = (const float4*)&zsh[wv][n][h * 32];     // broadcast reads
      const float4* mr = (const float4*)&muL[kk * 68 + h * 32];  // per-lane mu half-row
      float s0 = 0.f, s1 = 0.f;
#pragma unroll
      for (int j = 0; j < 8; ++j) {
        float4 zv = zr[j];
        float4 mv = mr[j];
        float a0 = zv.x - mv.x, a1 = zv.y - mv.y, a2 = zv.z - mv.z, a3 = zv.w - mv.w;
        s0 += a0 * a0 + a1 * a1;
        s1 += a2 * a2 + a3 * a3;
      }
      s = s0 + s1;
    }
    s += __shfl_xor(s, 32, 64);   // combine feature halves

    float qv = 0.f;
    if (lane < NK) {
      float tq = 1.0f / (1.0f + s * (1.0f / ALPHA) + 1e-8f);
      qv = exp2f((ALPHA + 1.0f) * __log2f(tq));   // /2 cancels in normalization
    }
    float ssum = qv;
    for (int o = 32; o; o >>= 1) ssum += __shfl_xor(ssum, o, 64);
    if (lane < NK) q[(size_t)(pid * 2 + n) * NK + lane] = qv / ssum;
  }
}

extern "C" void kernel_launch(void* const* d_in, const int* in_sizes, int n_in,
                              void* d_out, int out_size, void* d_ws, size_t ws_size,
                              hipStream_t stream) {
  const float* x  = (const float*)d_in[0];
  const void*  ei = d_in[1];
  const float* w  = (const float*)d_in[2];
  const float* W  = (const float*)d_in[3];
  const float* b  = (const float*)d_in[4];
  const float* mu = (const float*)d_in[5];

  char* ws = (char*)d_ws;
  int*   flag   = (int*)(ws + O_FLAG);
  int*   gcnt   = (int*)(ws + O_GCNT);
  float* dinv   = (float*)(ws + O_DINV);
  int*   hist   = (int*)(ws + O_HIST);
  int*   off    = (int*)(ws + O_OFF);
  int*   bcur   = (int*)(ws + O_BCUR);
  uint2* coarse = (uint2*)(ws + O_COARSE);
  int2*  epair  = (int2*)(ws + O_EPAIR);
  u16*   supb   = (u16*)(ws + O_SUP);

  float* z = (float*)d_out;
  float* q = (float*)d_out + (size_t)NN * NH;

  hipLaunchKernelGGL(k_detect, dim3(1),                   dim3(256), 0, stream, ei, flag, bcur, gcnt);
  hipLaunchKernelGGL(k_coarse, dim3((NE + CT - 1) / CT),  dim3(256), 0, stream, ei, flag, w, bcur, coarse);
  hipLaunchKernelGGL(k_sort,   dim3(NSB),                 dim3(256), 0, stream, coarse, bcur, gcnt, hist, dinv, off, epair);
  hipLaunchKernelGGL(k_gemm,   dim3((NN + GR - 1) / GR),  dim3(256), 0, stream, x, W, dinv, supb);
  hipLaunchKernelGGL(k_agg_q,  dim3((NN / 2 * 64) / 256), dim3(256), 0, stream, epair, off, hist, dinv, supb, b, mu, z, q);
}

// Round 18
// 145.462 us; speedup vs baseline: 1.2172x; 1.0074x over previous
//
#include <hip/hip_runtime.h>

#define NN 100000
#define NE 1600000
#define NF 128
#define NH 64
#define NK 20
#define SBK 512                     // sort-bucket: nodes per bucket
#define NSB ((NN + SBK - 1) / SBK)  // 196 buckets
#define CAP 9216                    // fixed coarse capacity per bucket (mean 8163 + 11.7 sigma)
#define CT 4096                     // edges per coarse-scatter block
#define PAD 8
#define GR 64                       // gemm rows per block (4 rows/thread)
#define MAXPAIRS (size_t(NE) + size_t(PAD) * NN)   // 2.4M pairs

static constexpr float ALPHA = 0.2f;

typedef unsigned short u16;
typedef unsigned int u32;

// ---- workspace layout (aligned to 256B) ----
constexpr size_t alup(size_t x) { return (x + 255) & ~size_t(255); }
constexpr size_t O_FLAG   = 0;                                    // 4 B
constexpr size_t O_GCNT   = 64;                                   // 4 B (epair allocator)
constexpr size_t O_DINV   = 256;                                  // NN f32
constexpr size_t O_HIST   = alup(O_DINV + size_t(NN) * 4);        // NN i32 (real counts)
constexpr size_t O_OFF    = alup(O_HIST + size_t(NN) * 4);        // NN i32 (segment starts)
constexpr size_t O_BCUR   = alup(O_OFF  + size_t(NN) * 4);        // NSB i32 (coarse cursors)
constexpr size_t O_COARSE = alup(O_BCUR + size_t(NSB) * 4);       // NSB*CAP uint2 (14.5 MB)
constexpr size_t O_EPAIR  = alup(O_COARSE + size_t(NSB) * CAP * 8); // MAXPAIRS int2 (19.2 MB)
constexpr size_t O_SUP    = alup(O_EPAIR + MAXPAIRS * 8);         // NN*NH bf16 (12.8 MB)
// total ~ 47.5 MB

__device__ __forceinline__ u16 f2bf(float f) {   // RNE float->bf16
  u32 u = __float_as_uint(f);
  u32 r = (u + 0x7fffu + ((u >> 16) & 1u)) >> 16;
  return (u16)r;
}

// edge_index dtype probe + init bucket cursors + zero epair allocator.
__global__ __launch_bounds__(256) void k_detect(const void* ei, int* flag, int* bcur, int* gcnt) {
  __shared__ int bad;
  if (threadIdx.x == 0) { bad = 0; *gcnt = 0; }
  if (threadIdx.x < NSB) bcur[threadIdx.x] = threadIdx.x * CAP;
  __syncthreads();
  const long long* p = (const long long*)ei;
  int ok = 1;
#pragma unroll
  for (int k = 0; k < 4; ++k) {
    long long v = p[threadIdx.x * 4 + k];
    if (v < 0 || v >= NN) ok = 0;
  }
  if (!ok) atomicOr(&bad, 1);
  __syncthreads();
  if (threadIdx.x == 0) *flag = bad ? 0 : 1;
}

// coarse scatter: bin edges by dst-bucket into fixed-capacity regions;
// LDS ranking -> contiguous writes; bucket frontier (196 lines) stays in L2.
__global__ __launch_bounds__(256) void k_coarse(const void* ei, const int* __restrict__ flag,
                                                const float* __restrict__ w,
                                                int* bcur, uint2* __restrict__ coarse) {
  __shared__ int lh[NSB];
  __shared__ int lbase[NSB];
  int t = threadIdx.x;
  for (int i = t; i < NSB; i += 256) lh[i] = 0;
  __syncthreads();
  int base = blockIdx.x * CT;
  int is64 = *flag;
  u32 key[16]; int wb[16], bk[16], lr[16];
#pragma unroll
  for (int k = 0; k < 16; ++k) {
    int e = base + k * 256 + t;
    if (e < NE) {
      int s, d;
      if (is64) { const long long* p = (const long long*)ei; s = (int)p[e]; d = (int)p[NE + e]; }
      else      { const int*       p = (const int*)ei;       s = p[e];      d = p[NE + e]; }
      int bb = d >> 9, dlo = d & 511;
      key[k] = (u32)s | ((u32)dlo << 17);     // src:17 | dlo:9
      wb[k]  = __float_as_int(w[e]);
      bk[k]  = bb;
      lr[k]  = atomicAdd(&lh[bb], 1);
    }
  }
  __syncthreads();
  if (t < NSB) { int c = lh[t]; if (c) lbase[t] = atomicAdd(&bcur[t], c); }
  __syncthreads();
#pragma unroll
  for (int k = 0; k < 16; ++k) {
    int e = base + k * 256 + t;
    if (e < NE) coarse[lbase[bk[k]] + lr[k]] = make_uint2(key[k], (u32)wb[k]);
  }
}

// merged nhist+scan+fine: pass 1 counts/weighted-degree from the bucket's
// coarse region; in-block scan of padded counts; bucket base allocated by
// global atomic; pass 2 re-reads coarse (L2-hot) and scatters into epair.
__global__ __launch_bounds__(256) void k_sort(const uint2* __restrict__ coarse,
                                              const int* __restrict__ bcur,
                                              int* __restrict__ gcnt,
                                              int* __restrict__ hist,
                                              float* __restrict__ dinv,
                                              int* __restrict__ off,
                                              int2* __restrict__ epair) {
  __shared__ int cnt[SBK];
  __shared__ float wsum[SBK];
  __shared__ int cur[SBK];
  __shared__ int endi[SBK];
  __shared__ int wtot[4];
  __shared__ int gbase;
  int t = threadIdx.x, b = blockIdx.x;
  for (int i = t; i < SBK; i += 256) { cnt[i] = 0; wsum[i] = 0.f; }
  __syncthreads();
  int s = b * CAP, e = bcur[b];
  for (int j = s + t; j < e; j += 256) {
    uint2 u = coarse[j];
    int dlo = u.x >> 17;
    atomicAdd(&cnt[dlo], 1);
    atomicAdd(&wsum[dlo], __uint_as_float(u.y));
  }
  __syncthreads();
  int n0 = b * SBK + t * 2, n1 = n0 + 1;
  int c0r = cnt[t * 2], c1r = cnt[t * 2 + 1];
  int c0 = (c0r + (PAD - 1)) & ~(PAD - 1);
  int c1 = (c1r + (PAD - 1)) & ~(PAD - 1);
  int sum2 = c0 + c1;
  int lane = t & 63, wv = t >> 6;
  int inc = sum2;
  for (int d = 1; d < 64; d <<= 1) { int tt = __shfl_up(inc, d, 64); if (lane >= d) inc += tt; }
  if (lane == 63) wtot[wv] = inc;
  __syncthreads();
  if (t == 0) gbase = atomicAdd(gcnt, wtot[0] + wtot[1] + wtot[2] + wtot[3]);
  int wbase = 0;
#pragma unroll
  for (int k = 0; k < 4; ++k) if (k < wv) wbase += wtot[k];
  __syncthreads();
  int base0 = gbase + wbase + (inc - sum2);
  int base1 = base0 + c0;
  if (n0 < NN) { off[n0] = base0; hist[n0] = c0r; dinv[n0] = rsqrtf(1.0f + wsum[t * 2]); }
  if (n1 < NN) { off[n1] = base1; hist[n1] = c1r; dinv[n1] = rsqrtf(1.0f + wsum[t * 2 + 1]); }
  cur[t * 2]      = base0;
  cur[t * 2 + 1]  = base1;
  endi[t * 2]     = base0 + c0;
  endi[t * 2 + 1] = base1 + c1;
  __syncthreads();
  for (int j = s + t; j < e; j += 256) {      // pass 2: L2-hot re-read
    uint2 u = coarse[j];
    int dlo = u.x >> 17;
    int src = u.x & 0x1FFFF;
    int pos = atomicAdd(&cur[dlo], 1);
    epair[pos] = make_int2(src, (int)u.y);
  }
  __syncthreads();
#pragma unroll
  for (int h = 0; h < 2; ++h) {               // fill pad tails with (0,0)
    int i = t * 2 + h;
    for (int p = cur[i]; p < endi[i]; ++p) epair[p] = make_int2(0, 0);
  }
}

// sup = bf16( dinv[:,None] * (x @ W) ) ; W (32KB) in LDS; 64 rows/block,
// 4 rows/thread, EXPLICIT 1-DEEP X-PREFETCH: xn (kk+1) loads issue before
// kk's 64-FMA block -> load-use distance ~130 cyc (round-17 lesson: gemm is
// x-L3-latency bound; occupancy alone gave only ~7us).
__global__ __launch_bounds__(256) void k_gemm(const float* __restrict__ x,
                                              const float* __restrict__ W,
                                              const float* __restrict__ dinv,
                                              u16* __restrict__ supb) {
  __shared__ float4 Wl[NF * NH / 4];
  const float4* Wg = (const float4*)W;
  for (int i = threadIdx.x; i < NF * NH / 4; i += 256) Wl[i] = Wg[i];
  __syncthreads();
  int lane16 = threadIdx.x & 15;   // column group: cols [lane16*4, lane16*4+4)
  int rowin  = threadIdx.x >> 4;   // 0..15
  const float4* x4 = (const float4*)x;
  int rowbase = blockIdx.x * GR;

  int r[4];
#pragma unroll
  for (int i = 0; i < 4; ++i) {
    int rr = rowbase + rowin + i * 16;
    r[i] = rr < NN ? rr : NN - 1;            // clamp: safe reads, stores predicated
  }
  float4 acc[4];
#pragma unroll
  for (int i = 0; i < 4; ++i) acc[i] = make_float4(0.f, 0.f, 0.f, 0.f);

  float4 xv[4], xn[4];
#pragma unroll
  for (int i = 0; i < 4; ++i) xv[i] = x4[r[i] * (NF / 4)];

  for (int kk = 0; kk < NF / 4 - 1; ++kk) {
#pragma unroll
    for (int i = 0; i < 4; ++i) xn[i] = x4[r[i] * (NF / 4) + kk + 1];  // prefetch kk+1
    float4 w0 = Wl[(4 * kk + 0) * 16 + lane16];
    float4 w1 = Wl[(4 * kk + 1) * 16 + lane16];
    float4 w2 = Wl[(4 * kk + 2) * 16 + lane16];
    float4 w3 = Wl[(4 * kk + 3) * 16 + lane16];
#pragma unroll
    for (int i = 0; i < 4; ++i) {
      float4 xvv = xv[i];
      acc[i].x += xvv.x * w0.x + xvv.y * w1.x + xvv.z * w2.x + xvv.w * w3.x;
      acc[i].y += xvv.x * w0.y + xvv.y * w1.y + xvv.z * w2.y + xvv.w * w3.y;
      acc[i].z += xvv.x * w0.z + xvv.y * w1.z + xvv.z * w2.z + xvv.w * w3.z;
      acc[i].w += xvv.x * w0.w + xvv.y * w1.w + xvv.z * w2.w + xvv.w * w3.w;
    }
#pragma unroll
    for (int i = 0; i < 4; ++i) xv[i] = xn[i];
  }
  {                                           // tail kk = 31 (no prefetch)
    int kk = NF / 4 - 1;
    float4 w0 = Wl[(4 * kk + 0) * 16 + lane16];
    float4 w1 = Wl[(4 * kk + 1) * 16 + lane16];
    float4 w2 = Wl[(4 * kk + 2) * 16 + lane16];
    float4 w3 = Wl[(4 * kk + 3) * 16 + lane16];
#pragma unroll
    for (int i = 0; i < 4; ++i) {
      float4 xvv = xv[i];
      acc[i].x += xvv.x * w0.x + xvv.y * w1.x + xvv.z * w2.x + xvv.w * w3.x;
      acc[i].y += xvv.x * w0.y + xvv.y * w1.y + xvv.z * w2.y + xvv.w * w3.y;
      acc[i].z += xvv.x * w0.z + xvv.y * w1.z + xvv.z * w2.z + xvv.w * w3.z;
      acc[i].w += xvv.x * w0.w + xvv.y * w1.w + xvv.z * w2.w + xvv.w * w3.w;
    }
  }

#pragma unroll
  for (int i = 0; i < 4; ++i) {
    int rr = rowbase + rowin + i * 16;
    if (rr < NN) {
      float di = dinv[rr];
      ushort4 o;
      o.x = f2bf(acc[i].x * di); o.y = f2bf(acc[i].y * di);
      o.z = f2bf(acc[i].z * di); o.w = f2bf(acc[i].w * di);
      *(ushort4*)&supb[(size_t)rr * NH + lane16 * 4] = o;
    }
  }
}

// TWO nodes per wave: lanes 0-31 = node 2p, lanes 32-63 = node 2p+1.
// Each lane covers 2 features (one dword = 2 bf16), so ONE VMEM gather
// serves a full 128B row for each half simultaneously (0.75 VMEM/edge).
// Each half loads its OWN epair stream; loop runs max(itersA, itersB).
// Head: 40-lane form run twice (once per node); same aggregate cost.
__global__ __launch_bounds__(256) void k_agg_q(const int2* __restrict__ epair,
                                               const int* __restrict__ off,
                                               const int* __restrict__ hist,
                                               const float* __restrict__ dinv,
                                               const u16* __restrict__ supb,
                                               const float* __restrict__ b,
                                               const float* __restrict__ mu,
                                               float* __restrict__ z,
                                               float* __restrict__ q) {
  __shared__ float muL[NK * 68];    // stride 68 words: f4-aligned, spreads banks
  __shared__ float zsh[4][2][64];
  for (int i = threadIdx.x; i < NK * NH; i += 256) muL[(i >> 6) * 68 + (i & 63)] = mu[i];
  __syncthreads();
  int pid  = (blockIdx.x * 256 + threadIdx.x) >> 6;  // node pair
  int lane = threadIdx.x & 63;
  int wv   = threadIdx.x >> 6;
  int hi   = lane >> 5;                              // which node of the pair
  int hl   = lane & 31;                              // feature pair index
  int node = pid * 2 + hi;

  int start = off[node];                             // uniform within half
  int cnt   = hist[node];
  int iters = ((cnt + (PAD - 1)) & ~(PAD - 1)) >> 3;
  int oit   = __shfl_xor(iters, 32, 64);
  int maxit = __builtin_amdgcn_readfirstlane(iters > oit ? iters : oit);
  float di  = dinv[node];
  u32 loff  = (u32)hl << 2;                          // dword offset in 128B row

  u32 su = *(const u32*)((const char*)supb + (((u32)node) << 7) + loff);  // self-loop
  float aLo = __uint_as_float(su << 16);
  float aHi = __uint_as_float(su & 0xffff0000u);

  for (int it = 0; it < maxit; ++it) {
    if (it < iters) {                                // per-half exec mask
      int j = start + it * 8;
      int4 p01 = *(const int4*)&epair[j + 0];
      int4 p23 = *(const int4*)&epair[j + 2];
      int4 p45 = *(const int4*)&epair[j + 4];
      int4 p67 = *(const int4*)&epair[j + 6];
      u32 u0 = *(const u32*)((const char*)supb + (((u32)p01.x) << 7) + loff);
      u32 u1 = *(const u32*)((const char*)supb + (((u32)p01.z) << 7) + loff);
      u32 u2 = *(const u32*)((const char*)supb + (((u32)p23.x) << 7) + loff);
      u32 u3 = *(const u32*)((const char*)supb + (((u32)p23.z) << 7) + loff);
      u32 u4 = *(const u32*)((const char*)supb + (((u32)p45.x) << 7) + loff);
      u32 u5 = *(const u32*)((const char*)supb + (((u32)p45.z) << 7) + loff);
      u32 u6 = *(const u32*)((const char*)supb + (((u32)p67.x) << 7) + loff);
      u32 u7 = *(const u32*)((const char*)supb + (((u32)p67.z) << 7) + loff);
      float w0 = __int_as_float(p01.y), w1 = __int_as_float(p01.w);
      float w2 = __int_as_float(p23.y), w3 = __int_as_float(p23.w);
      float w4 = __int_as_float(p45.y), w5 = __int_as_float(p45.w);
      float w6 = __int_as_float(p67.y), w7 = __int_as_float(p67.w);
      aLo += w0 * __uint_as_float(u0 << 16);
      aHi += w0 * __uint_as_float(u0 & 0xffff0000u);
      aLo += w1 * __uint_as_float(u1 << 16);
      aHi += w1 * __uint_as_float(u1 & 0xffff0000u);
      aLo += w2 * __uint_as_float(u2 << 16);
      aHi += w2 * __uint_as_float(u2 & 0xffff0000u);
      aLo += w3 * __uint_as_float(u3 << 16);
      aHi += w3 * __uint_as_float(u3 & 0xffff0000u);
      aLo += w4 * __uint_as_float(u4 << 16);
      aHi += w4 * __uint_as_float(u4 & 0xffff0000u);
      aLo += w5 * __uint_as_float(u5 << 16);
      aHi += w5 * __uint_as_float(u5 & 0xffff0000u);
      aLo += w6 * __uint_as_float(u6 << 16);
      aHi += w6 * __uint_as_float(u6 & 0xffff0000u);
      aLo += w7 * __uint_as_float(u7 << 16);
      aHi += w7 * __uint_as_float(u7 & 0xffff0000u);
    }
  }

  float2 bb = *(const float2*)&b[hl * 2];
  float zLo = di * aLo + bb.x;
  float zHi = di * aHi + bb.y;
  *(float2*)&z[(size_t)node * NH + hl * 2] = make_float2(zLo, zHi);
  *(float2*)&zsh[wv][hi][hl * 2] = make_float2(zLo, zHi);  // same-wave write->read

  // 40-lane head, run for each node of the pair
  int kk = lane & 31;
  int h  = lane >> 5;
#pragma unroll
  for (int n = 0; n < 2; ++n) {
    float s = 0.f;
    if (kk < NK) {
      const float4* zr = (const float4*)&zsh[wv][n][h * 32];     // broadcast reads
      const float4* mr = (const float4*)&muL[kk * 68 + h * 32];  // per-lane mu half-row
      float s0 = 0.f, s1 = 0.f;
#pragma unroll
      for (int j = 0; j < 8; ++j) {
        float4 zv = zr[j];
        float4 mv = mr[j];
        float a0 = zv.x - mv.x, a1 = zv.y - mv.y, a2 = zv.z - mv.z, a3 = zv.w - mv.w;
        s0 += a0 * a0 + a1 * a1;
        s1 += a2 * a2 + a3 * a3;
      }
      s = s0 + s1;
    }
    s += __shfl_xor(s, 32, 64);   // combine feature halves

    float qv = 0.f;
    if (lane < NK) {
      float tq = 1.0f / (1.0f + s * (1.0f / ALPHA) + 1e-8f);
      qv = exp2f((ALPHA + 1.0f) * __log2f(tq));   // /2 cancels in normalization
    }
    float ssum = qv;
    for (int o = 32; o; o >>= 1) ssum += __shfl_xor(ssum, o, 64);
    if (lane < NK) q[(size_t)(pid * 2 + n) * NK + lane] = qv / ssum;
  }
}

extern "C" void kernel_launch(void* const* d_in, const int* in_sizes, int n_in,
                              void* d_out, int out_size, void* d_ws, size_t ws_size,
                              hipStream_t stream) {
  const float* x  = (const float*)d_in[0];
  const void*  ei = d_in[1];
  const float* w  = (const float*)d_in[2];
  const float* W  = (const float*)d_in[3];
  const float* b  = (const float*)d_in[4];
  const float* mu = (const float*)d_in[5];

  char* ws = (char*)d_ws;
  int*   flag   = (int*)(ws + O_FLAG);
  int*   gcnt   = (int*)(ws + O_GCNT);
  float* dinv   = (float*)(ws + O_DINV);
  int*   hist   = (int*)(ws + O_HIST);
  int*   off    = (int*)(ws + O_OFF);
  int*   bcur   = (int*)(ws + O_BCUR);
  uint2* coarse = (uint2*)(ws + O_COARSE);
  int2*  epair  = (int2*)(ws + O_EPAIR);
  u16*   supb   = (u16*)(ws + O_SUP);

  float* z = (float*)d_out;
  float* q = (float*)d_out + (size_t)NN * NH;

  hipLaunchKernelGGL(k_detect, dim3(1),                   dim3(256), 0, stream, ei, flag, bcur, gcnt);
  hipLaunchKernelGGL(k_coarse, dim3((NE + CT - 1) / CT),  dim3(256), 0, stream, ei, flag, w, bcur, coarse);
  hipLaunchKernelGGL(k_sort,   dim3(NSB),                 dim3(256), 0, stream, coarse, bcur, gcnt, hist, dinv, off, epair);
  hipLaunchKernelGGL(k_gemm,   dim3((NN + GR - 1) / GR),  dim3(256), 0, stream, x, W, dinv, supb);
  hipLaunchKernelGGL(k_agg_q,  dim3((NN / 2 * 64) / 256), dim3(256), 0, stream, epair, off, hist, dinv, supb, b, mu, z, q);
}

// Round 19
// 142.003 us; speedup vs baseline: 1.2468x; 1.0244x over previous
//
#include <hip/hip_runtime.h>

#define NN 100000
#define NE 1600000
#define NF 128
#define NH 64
#define NK 20
#define SBK 512                     // sort-bucket: nodes per bucket
#define NSB ((NN + SBK - 1) / SBK)  // 196 buckets
#define CAP 9216                    // fixed coarse capacity per bucket (mean 8163 + 11.7 sigma)
#define CT 4096                     // edges per coarse-scatter block
#define PAD 4
#define GR 64                       // gemm rows per block (4 rows/thread)
#define MAXPAIRS (size_t(NE) + size_t(PAD) * NN)   // 2.0M pairs

static constexpr float ALPHA = 0.2f;

typedef unsigned short u16;
typedef unsigned int u32;

// ---- workspace layout (aligned to 256B) ----
constexpr size_t alup(size_t x) { return (x + 255) & ~size_t(255); }
constexpr size_t O_FLAG   = 0;                                    // 4 B
constexpr size_t O_GCNT   = 64;                                   // 4 B (epair allocator)
constexpr size_t O_DINV   = 256;                                  // NN f32
constexpr size_t O_HIST   = alup(O_DINV + size_t(NN) * 4);        // NN i32 (real counts)
constexpr size_t O_OFF    = alup(O_HIST + size_t(NN) * 4);        // NN i32 (segment starts)
constexpr size_t O_BCUR   = alup(O_OFF  + size_t(NN) * 4);        // NSB i32 (coarse cursors)
constexpr size_t O_COARSE = alup(O_BCUR + size_t(NSB) * 4);       // NSB*CAP uint2 (14.5 MB)
constexpr size_t O_EPAIR  = alup(O_COARSE + size_t(NSB) * CAP * 8); // MAXPAIRS int2 (16 MB)
constexpr size_t O_SUP    = alup(O_EPAIR + MAXPAIRS * 8);         // NN*NH bf16 (12.8 MB)
// total ~ 44 MB

__device__ __forceinline__ u16 f2bf(float f) {   // RNE float->bf16
  u32 u = __float_as_uint(f);
  u32 r = (u + 0x7fffu + ((u >> 16) & 1u)) >> 16;
  return (u16)r;
}

// edge_index dtype probe + init bucket cursors + zero epair allocator.
__global__ __launch_bounds__(256) void k_detect(const void* ei, int* flag, int* bcur, int* gcnt) {
  __shared__ int bad;
  if (threadIdx.x == 0) { bad = 0; *gcnt = 0; }
  if (threadIdx.x < NSB) bcur[threadIdx.x] = threadIdx.x * CAP;
  __syncthreads();
  const long long* p = (const long long*)ei;
  int ok = 1;
#pragma unroll
  for (int k = 0; k < 4; ++k) {
    long long v = p[threadIdx.x * 4 + k];
    if (v < 0 || v >= NN) ok = 0;
  }
  if (!ok) atomicOr(&bad, 1);
  __syncthreads();
  if (threadIdx.x == 0) *flag = bad ? 0 : 1;
}

// coarse scatter: bin edges by dst-bucket into fixed-capacity regions;
// LDS ranking -> contiguous writes; bucket frontier (196 lines) stays in L2.
__global__ __launch_bounds__(256) void k_coarse(const void* ei, const int* __restrict__ flag,
                                                const float* __restrict__ w,
                                                int* bcur, uint2* __restrict__ coarse) {
  __shared__ int lh[NSB];
  __shared__ int lbase[NSB];
  int t = threadIdx.x;
  for (int i = t; i < NSB; i += 256) lh[i] = 0;
  __syncthreads();
  int base = blockIdx.x * CT;
  int is64 = *flag;
  u32 key[16]; int wb[16], bk[16], lr[16];
#pragma unroll
  for (int k = 0; k < 16; ++k) {
    int e = base + k * 256 + t;
    if (e < NE) {
      int s, d;
      if (is64) { const long long* p = (const long long*)ei; s = (int)p[e]; d = (int)p[NE + e]; }
      else      { const int*       p = (const int*)ei;       s = p[e];      d = p[NE + e]; }
      int bb = d >> 9, dlo = d & 511;
      key[k] = (u32)s | ((u32)dlo << 17);     // src:17 | dlo:9
      wb[k]  = __float_as_int(w[e]);
      bk[k]  = bb;
      lr[k]  = atomicAdd(&lh[bb], 1);
    }
  }
  __syncthreads();
  if (t < NSB) { int c = lh[t]; if (c) lbase[t] = atomicAdd(&bcur[t], c); }
  __syncthreads();
#pragma unroll
  for (int k = 0; k < 16; ++k) {
    int e = base + k * 256 + t;
    if (e < NE) coarse[lbase[bk[k]] + lr[k]] = make_uint2(key[k], (u32)wb[k]);
  }
}

// merged nhist+scan+fine: pass 1 counts/weighted-degree from the bucket's
// coarse region; in-block scan of padded counts; bucket base allocated by
// global atomic; pass 2 re-reads coarse (L2-hot) and scatters into epair.
__global__ __launch_bounds__(256) void k_sort(const uint2* __restrict__ coarse,
                                              const int* __restrict__ bcur,
                                              int* __restrict__ gcnt,
                                              int* __restrict__ hist,
                                              float* __restrict__ dinv,
                                              int* __restrict__ off,
                                              int2* __restrict__ epair) {
  __shared__ int cnt[SBK];
  __shared__ float wsum[SBK];
  __shared__ int cur[SBK];
  __shared__ int endi[SBK];
  __shared__ int wtot[4];
  __shared__ int gbase;
  int t = threadIdx.x, b = blockIdx.x;
  for (int i = t; i < SBK; i += 256) { cnt[i] = 0; wsum[i] = 0.f; }
  __syncthreads();
  int s = b * CAP, e = bcur[b];
  for (int j = s + t; j < e; j += 256) {
    uint2 u = coarse[j];
    int dlo = u.x >> 17;
    atomicAdd(&cnt[dlo], 1);
    atomicAdd(&wsum[dlo], __uint_as_float(u.y));
  }
  __syncthreads();
  int n0 = b * SBK + t * 2, n1 = n0 + 1;
  int c0r = cnt[t * 2], c1r = cnt[t * 2 + 1];
  int c0 = (c0r + (PAD - 1)) & ~(PAD - 1);
  int c1 = (c1r + (PAD - 1)) & ~(PAD - 1);
  int sum2 = c0 + c1;
  int lane = t & 63, wv = t >> 6;
  int inc = sum2;
  for (int d = 1; d < 64; d <<= 1) { int tt = __shfl_up(inc, d, 64); if (lane >= d) inc += tt; }
  if (lane == 63) wtot[wv] = inc;
  __syncthreads();
  if (t == 0) gbase = atomicAdd(gcnt, wtot[0] + wtot[1] + wtot[2] + wtot[3]);
  int wbase = 0;
#pragma unroll
  for (int k = 0; k < 4; ++k) if (k < wv) wbase += wtot[k];
  __syncthreads();
  int base0 = gbase + wbase + (inc - sum2);
  int base1 = base0 + c0;
  if (n0 < NN) { off[n0] = base0; hist[n0] = c0r; dinv[n0] = rsqrtf(1.0f + wsum[t * 2]); }
  if (n1 < NN) { off[n1] = base1; hist[n1] = c1r; dinv[n1] = rsqrtf(1.0f + wsum[t * 2 + 1]); }
  cur[t * 2]      = base0;
  cur[t * 2 + 1]  = base1;
  endi[t * 2]     = base0 + c0;
  endi[t * 2 + 1] = base1 + c1;
  __syncthreads();
  for (int j = s + t; j < e; j += 256) {      // pass 2: L2-hot re-read
    uint2 u = coarse[j];
    int dlo = u.x >> 17;
    int src = u.x & 0x1FFFF;
    int pos = atomicAdd(&cur[dlo], 1);
    epair[pos] = make_int2(src, (int)u.y);
  }
  __syncthreads();
#pragma unroll
  for (int h = 0; h < 2; ++h) {               // fill pad tails with (0,0): <= 3 each
    int i = t * 2 + h;
    for (int p = cur[i]; p < endi[i]; ++p) epair[p] = make_int2(0, 0);
  }
}

// sup = bf16( dinv[:,None] * (x @ W) ) ; W (32KB) in LDS; 64 rows/block,
// 4 rows/thread, 1-deep x-prefetch (W reads amortized over 4 rows).
__global__ __launch_bounds__(256) void k_gemm(const float* __restrict__ x,
                                              const float* __restrict__ W,
                                              const float* __restrict__ dinv,
                                              u16* __restrict__ supb) {
  __shared__ float4 Wl[NF * NH / 4];
  const float4* Wg = (const float4*)W;
  for (int i = threadIdx.x; i < NF * NH / 4; i += 256) Wl[i] = Wg[i];
  __syncthreads();
  int lane16 = threadIdx.x & 15;   // column group: cols [lane16*4, lane16*4+4)
  int rowin  = threadIdx.x >> 4;   // 0..15
  const float4* x4 = (const float4*)x;
  int rowbase = blockIdx.x * GR;

  int r[4];
#pragma unroll
  for (int i = 0; i < 4; ++i) {
    int rr = rowbase + rowin + i * 16;
    r[i] = rr < NN ? rr : NN - 1;            // clamp: safe reads, stores predicated
  }
  float4 acc[4];
#pragma unroll
  for (int i = 0; i < 4; ++i) acc[i] = make_float4(0.f, 0.f, 0.f, 0.f);

  float4 xv[4], xn[4];
#pragma unroll
  for (int i = 0; i < 4; ++i) xv[i] = x4[r[i] * (NF / 4)];

  for (int kk = 0; kk < NF / 4 - 1; ++kk) {
#pragma unroll
    for (int i = 0; i < 4; ++i) xn[i] = x4[r[i] * (NF / 4) + kk + 1];  // prefetch kk+1
    float4 w0 = Wl[(4 * kk + 0) * 16 + lane16];
    float4 w1 = Wl[(4 * kk + 1) * 16 + lane16];
    float4 w2 = Wl[(4 * kk + 2) * 16 + lane16];
    float4 w3 = Wl[(4 * kk + 3) * 16 + lane16];
#pragma unroll
    for (int i = 0; i < 4; ++i) {
      float4 xvv = xv[i];
      acc[i].x += xvv.x * w0.x + xvv.y * w1.x + xvv.z * w2.x + xvv.w * w3.x;
      acc[i].y += xvv.x * w0.y + xvv.y * w1.y + xvv.z * w2.y + xvv.w * w3.y;
      acc[i].z += xvv.x * w0.z + xvv.y * w1.z + xvv.z * w2.z + xvv.w * w3.z;
      acc[i].w += xvv.x * w0.w + xvv.y * w1.w + xvv.z * w2.w + xvv.w * w3.w;
    }
#pragma unroll
    for (int i = 0; i < 4; ++i) xv[i] = xn[i];
  }
  {                                           // tail kk = 31 (no prefetch)
    int kk = NF / 4 - 1;
    float4 w0 = Wl[(4 * kk + 0) * 16 + lane16];
    float4 w1 = Wl[(4 * kk + 1) * 16 + lane16];
    float4 w2 = Wl[(4 * kk + 2) * 16 + lane16];
    float4 w3 = Wl[(4 * kk + 3) * 16 + lane16];
#pragma unroll
    for (int i = 0; i < 4; ++i) {
      float4 xvv = xv[i];
      acc[i].x += xvv.x * w0.x + xvv.y * w1.x + xvv.z * w2.x + xvv.w * w3.x;
      acc[i].y += xvv.x * w0.y + xvv.y * w1.y + xvv.z * w2.y + xvv.w * w3.y;
      acc[i].z += xvv.x * w0.z + xvv.y * w1.z + xvv.z * w2.z + xvv.w * w3.z;
      acc[i].w += xvv.x * w0.w + xvv.y * w1.w + xvv.z * w2.w + xvv.w * w3.w;
    }
  }

#pragma unroll
  for (int i = 0; i < 4; ++i) {
    int rr = rowbase + rowin + i * 16;
    if (rr < NN) {
      float di = dinv[rr];
      ushort4 o;
      o.x = f2bf(acc[i].x * di); o.y = f2bf(acc[i].y * di);
      o.z = f2bf(acc[i].z * di); o.w = f2bf(acc[i].w * di);
      *(ushort4*)&supb[(size_t)rr * NH + lane16 * 4] = o;
    }
  }
}

// TWO nodes per wave: lanes 0-31 = node 2p, lanes 32-63 = node 2p+1.
// Each lane covers 2 features (one dword = 2 bf16), so ONE VMEM gather
// serves a full 128B row for each half simultaneously. PAD=4: 8-edge
// unrolled body for full octets + single 4-edge tail (segments are exact
// multiples of 4) -> ~12% fewer phantom pad-edge gathers than PAD=8.
__global__ __launch_bounds__(256) void k_agg_q(const int2* __restrict__ epair,
                                               const int* __restrict__ off,
                                               const int* __restrict__ hist,
                                               const float* __restrict__ dinv,
                                               const u16* __restrict__ supb,
                                               const float* __restrict__ b,
                                               const float* __restrict__ mu,
                                               float* __restrict__ z,
                                               float* __restrict__ q) {
  __shared__ float muL[NK * 68];    // stride 68 words: f4-aligned, spreads banks
  __shared__ float zsh[4][2][64];
  for (int i = threadIdx.x; i < NK * NH; i += 256) muL[(i >> 6) * 68 + (i & 63)] = mu[i];
  __syncthreads();
  int pid  = (blockIdx.x * 256 + threadIdx.x) >> 6;  // node pair
  int lane = threadIdx.x & 63;
  int wv   = threadIdx.x >> 6;
  int hi   = lane >> 5;                              // which node of the pair
  int hl   = lane & 31;                              // feature pair index
  int node = pid * 2 + hi;

  int start = off[node];                             // uniform within half
  int cnt   = hist[node];
  int endU  = start + ((cnt + (PAD - 1)) & ~(PAD - 1));
  float di  = dinv[node];
  u32 loff  = (u32)hl << 2;                          // dword offset in 128B row

  u32 su = *(const u32*)((const char*)supb + (((u32)node) << 7) + loff);  // self-loop
  float aLo = __uint_as_float(su << 16);
  float aHi = __uint_as_float(su & 0xffff0000u);

  int j = start;
  for (; j + 8 <= endU; j += 8) {                    // divergent bound: exec-masked
    int4 p01 = *(const int4*)&epair[j + 0];
    int4 p23 = *(const int4*)&epair[j + 2];
    int4 p45 = *(const int4*)&epair[j + 4];
    int4 p67 = *(const int4*)&epair[j + 6];
    u32 u0 = *(const u32*)((const char*)supb + (((u32)p01.x) << 7) + loff);
    u32 u1 = *(const u32*)((const char*)supb + (((u32)p01.z) << 7) + loff);
    u32 u2 = *(const u32*)((const char*)supb + (((u32)p23.x) << 7) + loff);
    u32 u3 = *(const u32*)((const char*)supb + (((u32)p23.z) << 7) + loff);
    u32 u4 = *(const u32*)((const char*)supb + (((u32)p45.x) << 7) + loff);
    u32 u5 = *(const u32*)((const char*)supb + (((u32)p45.z) << 7) + loff);
    u32 u6 = *(const u32*)((const char*)supb + (((u32)p67.x) << 7) + loff);
    u32 u7 = *(const u32*)((const char*)supb + (((u32)p67.z) << 7) + loff);
    float w0 = __int_as_float(p01.y), w1 = __int_as_float(p01.w);
    float w2 = __int_as_float(p23.y), w3 = __int_as_float(p23.w);
    float w4 = __int_as_float(p45.y), w5 = __int_as_float(p45.w);
    float w6 = __int_as_float(p67.y), w7 = __int_as_float(p67.w);
    aLo += w0 * __uint_as_float(u0 << 16);
    aHi += w0 * __uint_as_float(u0 & 0xffff0000u);
    aLo += w1 * __uint_as_float(u1 << 16);
    aHi += w1 * __uint_as_float(u1 & 0xffff0000u);
    aLo += w2 * __uint_as_float(u2 << 16);
    aHi += w2 * __uint_as_float(u2 & 0xffff0000u);
    aLo += w3 * __uint_as_float(u3 << 16);
    aHi += w3 * __uint_as_float(u3 & 0xffff0000u);
    aLo += w4 * __uint_as_float(u4 << 16);
    aHi += w4 * __uint_as_float(u4 & 0xffff0000u);
    aLo += w5 * __uint_as_float(u5 << 16);
    aHi += w5 * __uint_as_float(u5 & 0xffff0000u);
    aLo += w6 * __uint_as_float(u6 << 16);
    aHi += w6 * __uint_as_float(u6 & 0xffff0000u);
    aLo += w7 * __uint_as_float(u7 << 16);
    aHi += w7 * __uint_as_float(u7 & 0xffff0000u);
  }
  if (j < endU) {                                    // exact 4-edge tail
    int4 p01 = *(const int4*)&epair[j + 0];
    int4 p23 = *(const int4*)&epair[j + 2];
    u32 u0 = *(const u32*)((const char*)supb + (((u32)p01.x) << 7) + loff);
    u32 u1 = *(const u32*)((const char*)supb + (((u32)p01.z) << 7) + loff);
    u32 u2 = *(const u32*)((const char*)supb + (((u32)p23.x) << 7) + loff);
    u32 u3 = *(const u32*)((const char*)supb + (((u32)p23.z) << 7) + loff);
    float w0 = __int_as_float(p01.y), w1 = __int_as_float(p01.w);
    float w2 = __int_as_float(p23.y), w3 = __int_as_float(p23.w);
    aLo += w0 * __uint_as_float(u0 << 16);
    aHi += w0 * __uint_as_float(u0 & 0xffff0000u);
    aLo += w1 * __uint_as_float(u1 << 16);
    aHi += w1 * __uint_as_float(u1 & 0xffff0000u);
    aLo += w2 * __uint_as_float(u2 << 16);
    aHi += w2 * __uint_as_float(u2 & 0xffff0000u);
    aLo += w3 * __uint_as_float(u3 << 16);
    aHi += w3 * __uint_as_float(u3 & 0xffff0000u);
  }

  float2 bb = *(const float2*)&b[hl * 2];
  float zLo = di * aLo + bb.x;
  float zHi = di * aHi + bb.y;
  *(float2*)&z[(size_t)node * NH + hl * 2] = make_float2(zLo, zHi);
  *(float2*)&zsh[wv][hi][hl * 2] = make_float2(zLo, zHi);  // same-wave write->read

  // 40-lane head, run for each node of the pair
  int kk = lane & 31;
  int h  = lane >> 5;
#pragma unroll
  for (int n = 0; n < 2; ++n) {
    float s = 0.f;
    if (kk < NK) {
      const float4* zr = (const float4*)&zsh[wv][n][h * 32];     // broadcast reads
      const float4* mr = (const float4*)&muL[kk * 68 + h * 32];  // per-lane mu half-row
      float s0 = 0.f, s1 = 0.f;
#pragma unroll
      for (int j2 = 0; j2 < 8; ++j2) {
        float4 zv = zr[j2];
        float4 mv = mr[j2];
        float a0 = zv.x - mv.x, a1 = zv.y - mv.y, a2 = zv.z - mv.z, a3 = zv.w - mv.w;
        s0 += a0 * a0 + a1 * a1;
        s1 += a2 * a2 + a3 * a3;
      }
      s = s0 + s1;
    }
    s += __shfl_xor(s, 32, 64);   // combine feature halves

    float qv = 0.f;
    if (lane < NK) {
      float tq = 1.0f / (1.0f + s * (1.0f / ALPHA) + 1e-8f);
      qv = exp2f((ALPHA + 1.0f) * __log2f(tq));   // /2 cancels in normalization
    }
    float ssum = qv;
    for (int o = 32; o; o >>= 1) ssum += __shfl_xor(ssum, o, 64);
    if (lane < NK) q[(size_t)(pid * 2 + n) * NK + lane] = qv / ssum;
  }
}

extern "C" void kernel_launch(void* const* d_in, const int* in_sizes, int n_in,
                              void* d_out, int out_size, void* d_ws, size_t ws_size,
                              hipStream_t stream) {
  const float* x  = (const float*)d_in[0];
  const void*  ei = d_in[1];
  const float* w  = (const float*)d_in[2];
  const float* W  = (const float*)d_in[3];
  const float* b  = (const float*)d_in[4];
  const float* mu = (const float*)d_in[5];

  char* ws = (char*)d_ws;
  int*   flag   = (int*)(ws + O_FLAG);
  int*   gcnt   = (int*)(ws + O_GCNT);
  float* dinv   = (float*)(ws + O_DINV);
  int*   hist   = (int*)(ws + O_HIST);
  int*   off    = (int*)(ws + O_OFF);
  int*   bcur   = (int*)(ws + O_BCUR);
  uint2* coarse = (uint2*)(ws + O_COARSE);
  int2*  epair  = (int2*)(ws + O_EPAIR);
  u16*   supb   = (u16*)(ws + O_SUP);

  float* z = (float*)d_out;
  float* q = (float*)d_out + (size_t)NN * NH;

  hipLaunchKernelGGL(k_detect, dim3(1),                   dim3(256), 0, stream, ei, flag, bcur, gcnt);
  hipLaunchKernelGGL(k_coarse, dim3((NE + CT - 1) / CT),  dim3(256), 0, stream, ei, flag, w, bcur, coarse);
  hipLaunchKernelGGL(k_sort,   dim3(NSB),                 dim3(256), 0, stream, coarse, bcur, gcnt, hist, dinv, off, epair);
  hipLaunchKernelGGL(k_gemm,   dim3((NN + GR - 1) / GR),  dim3(256), 0, stream, x, W, dinv, supb);
  hipLaunchKernelGGL(k_agg_q,  dim3((NN / 2 * 64) / 256), dim3(256), 0, stream, epair, off, hist, dinv, supb, b, mu, z, q);
}